// Round 12
// baseline (524.146 us; speedup 1.0000x reference)
//
#include <hip/hip_runtime.h>
#include <hip/hip_bf16.h>
#include <math.h>

#define HID 128
#define NUM_G 20
#define EF 4
#define NN 20000
#define NE 640000
#define KN1 256           // node GEMM1 K
#define TS 136            // LDS stride (bf16): 272B rows -> near-conflict-free

typedef __attribute__((ext_vector_type(8))) short short8;
typedef __attribute__((ext_vector_type(4))) short short4v;
typedef __attribute__((ext_vector_type(4))) float floatx4;
typedef __attribute__((ext_vector_type(4))) unsigned int uintx4;

__device__ __forceinline__ float silu_f(float v){
    return v * __builtin_amdgcn_rcpf(1.0f + __expf(-v));
}
__device__ __forceinline__ float sigm_f(float v){
    return __builtin_amdgcn_rcpf(1.0f + __expf(-v));
}
__device__ __forceinline__ float tanh_f(float v){
    return 1.0f - 2.0f * __builtin_amdgcn_rcpf(1.0f + __expf(2.0f * v));
}
__device__ __forceinline__ unsigned short f2bf(float v){
    unsigned int u = __float_as_uint(v);
    u = (u + 0x7fffu + ((u >> 16) & 1u)) >> 16;
    return (unsigned short)u;
}
__device__ __forceinline__ float bf2f(unsigned short u){
    return __uint_as_float(((unsigned int)u) << 16);
}
__device__ __forceinline__ unsigned int pk2(float a, float b){
    __hip_bfloat162 h = __float22bfloat162_rn(make_float2(a, b));
    return *(unsigned int*)&h;
}
__device__ __forceinline__ float2 up2(unsigned int u){
    __hip_bfloat162 h = *(__hip_bfloat162*)&u;
    return __bfloat1622float2(h);
}

// ---- Kernel A: weight transpose (blocks 0..127) ∥ dst histogram (128..2127)
//                ∥ zero agg+dxv (2128..4174) ----
#define ZERO_F4 ((NN*HID + NN*3 + 3) / 4)          // 655000 float4s
#define A_ZBLK ((ZERO_F4 + 319) / 320)             // 2047
__global__ __launch_bounds__(320) void prep_all_kernel(
    const float* __restrict__ W_e1, const float* __restrict__ W_e2,
    const float* __restrict__ W_x1, const float* __restrict__ W_n1,
    const float* __restrict__ W_n2,
    unsigned short* __restrict__ WT1d, unsigned short* __restrict__ WT1s,
    unsigned short* __restrict__ WT1r,
    unsigned short* __restrict__ WT_e2, unsigned short* __restrict__ WT_x1,
    unsigned short* __restrict__ WT_n1, unsigned short* __restrict__ WT_n2,
    const int* __restrict__ edge_index, int* __restrict__ counts,
    float4* __restrict__ zbase)
{
    int t = threadIdx.x;
    int b = blockIdx.x;
    if (b < 128) {
        int n = b;
        if (t < HID) {
            WT1d[n*HID + t] = f2bf(W_e1[t*HID + n]);
            WT1s[n*HID + t] = f2bf(W_e1[(HID+t)*HID + n]);
            WT_e2[n*HID + t] = f2bf(W_e2[t*HID + n]);
            WT_x1[n*HID + t] = f2bf(W_x1[t*HID + n]);
            WT_n2[n*HID + t] = f2bf(W_n2[t*HID + n]);
        }
        if (t < 32) WT1r[n*32 + t] = (t < NUM_G+EF) ? f2bf(W_e1[(256+t)*HID + n]) : (unsigned short)0;
        if (t < KN1) WT_n1[n*KN1 + t] = f2bf(W_n1[t*HID + n]);
    } else if (b < 2128) {
        int e = (b - 128) * 320 + t;   // NE = 2000*320
        atomicAdd(&counts[edge_index[NE + e]], 1);
    } else {
        int idx = (b - 2128) * 320 + t;
        if (idx < ZERO_F4) zbase[idx] = make_float4(0.f, 0.f, 0.f, 0.f);
    }
}

__global__ __launch_bounds__(1024) void scan_kernel(
    const int* __restrict__ counts, int* __restrict__ cursor)
{
    __shared__ int part[1024];
    const int t = threadIdx.x;
    const int CH = (NN + 1023) / 1024;   // 20
    int base = t * CH;
    int s = 0;
    for (int i = 0; i < CH; ++i) { int idx = base + i; if (idx < NN) s += counts[idx]; }
    part[t] = s; __syncthreads();
    for (int off = 1; off < 1024; off <<= 1) {
        int v = (t >= off) ? part[t - off] : 0;
        __syncthreads();
        part[t] += v;
        __syncthreads();
    }
    int run = (t == 0) ? 0 : part[t - 1];
    for (int i = 0; i < CH; ++i) {
        int idx = base + i;
        if (idx < NN) { cursor[idx] = run; run += counts[idx]; }
    }
}

// ---- Kernel C: pd (blocks 0..312, 4 waves x 16 nodes) ∥ build (blocks 313+) ----
#define PD_BLOCKS ((NN + 63) / 64)    // 313
__global__ __launch_bounds__(256) void build_pd_kernel(
    const int* __restrict__ edge_index, const float* __restrict__ x,
    const float* __restrict__ edge_attr, int* __restrict__ cursor,
    int2* __restrict__ pair2, float4* __restrict__ geom4,
    unsigned short* __restrict__ attrb,
    const float* __restrict__ h, const float* __restrict__ b_e1,
    const unsigned short* __restrict__ WT1d, const unsigned short* __restrict__ WT1s,
    unsigned short* __restrict__ PD, unsigned short* __restrict__ PS)
{
    __shared__ __align__(16) unsigned short T[4][16*TS];

    if (blockIdx.x >= PD_BLOCKS) {
        // ---- build part ----
        int e = (blockIdx.x - PD_BLOCKS) * 256 + threadIdx.x;
        int s = edge_index[e];
        int d = edge_index[NE + e];
        int pos = atomicAdd(&cursor[d], 1);
        float rx = x[d*3+0] - x[s*3+0];
        float ry = x[d*3+1] - x[s*3+1];
        float rz = x[d*3+2] - x[s*3+2];
        float r  = sqrtf(rx*rx + ry*ry + rz*rz + 1e-8f);
        pair2[pos] = make_int2(s, d);
        geom4[pos] = make_float4(rx, ry, rz, r);
        short4v a;
        #pragma unroll
        for (int j = 0; j < 4; ++j) a[j] = (short)f2bf(edge_attr[(size_t)e*EF + j]);
        *(short4v*)(attrb + (size_t)pos*4) = a;
        return;
    }

    // ---- pd part: 4 autonomous waves, 16 nodes each ----
    const int wv   = threadIdx.x >> 6;
    const int lane = threadIdx.x & 63;
    const int quad = lane >> 4;
    const int l15  = lane & 15;
    int node = blockIdx.x * 64 + wv * 16 + l15;
    if (node >= NN) node = NN - 1;     // duplicate-write guard (same data)
    unsigned short* Tw = &T[wv][0];

    short8 ah[4];
    #pragma unroll
    for (int kc = 0; kc < 4; ++kc) {
        const float* p = h + (size_t)node*HID + kc*32 + quad*8;
        float4 f0 = *(const float4*)(p);
        float4 f1 = *(const float4*)(p + 4);
        uintx4 u;
        u[0] = pk2(f0.x, f0.y); u[1] = pk2(f0.z, f0.w);
        u[2] = pk2(f1.x, f1.y); u[3] = pk2(f1.z, f1.w);
        ah[kc] = __builtin_bit_cast(short8, u);
    }

    floatx4 ad[8], as[8];
    #pragma unroll
    for (int t = 0; t < 8; ++t) { ad[t] = (floatx4){0,0,0,0}; as[t] = (floatx4){0,0,0,0}; }
    #pragma unroll
    for (int kc = 0; kc < 4; ++kc) {
        #pragma unroll
        for (int t = 0; t < 8; ++t) {
            short8 bd = *(const short8*)(WT1d + (size_t)(t*16+l15)*HID + kc*32 + quad*8);
            short8 bs = *(const short8*)(WT1s + (size_t)(t*16+l15)*HID + kc*32 + quad*8);
            ad[t] = __builtin_amdgcn_mfma_f32_16x16x32_bf16(ah[kc], bd, ad[t], 0, 0, 0);
            as[t] = __builtin_amdgcn_mfma_f32_16x16x32_bf16(ah[kc], bs, as[t], 0, 0, 0);
        }
    }
    #pragma unroll
    for (int t = 0; t < 8; ++t) {
        int col = t*16 + l15;
        float bv = b_e1[col];
        #pragma unroll
        for (int i = 0; i < 4; ++i)
            Tw[(quad*4+i)*TS + col] = f2bf(ad[t][i] + bv);
    }
    __builtin_amdgcn_wave_barrier();
    #pragma unroll
    for (int kc = 0; kc < 4; ++kc)
        *(short8*)(PD + (size_t)node*HID + kc*32 + quad*8) =
            *(const short8*)(&Tw[l15*TS + kc*32 + quad*8]);
    __builtin_amdgcn_wave_barrier();
    #pragma unroll
    for (int t = 0; t < 8; ++t) {
        int col = t*16 + l15;
        #pragma unroll
        for (int i = 0; i < 4; ++i)
            Tw[(quad*4+i)*TS + col] = f2bf(as[t][i]);
    }
    __builtin_amdgcn_wave_barrier();
    #pragma unroll
    for (int kc = 0; kc < 4; ++kc)
        *(short8*)(PS + (size_t)node*HID + kc*32 + quad*8) =
            *(const short8*)(&Tw[l15*TS + kc*32 + quad*8]);
}

// ---- edge kernel: 128 threads = 2 autonomous waves, 32 sorted edges/wave.
// launch_bounds (128,3): arg=4 clamps VGPR to 64 -> spill cliff (R6/R10); arg=3 ok.
__global__ __launch_bounds__(128, 3) void egnn_edge_mfma(
    const int2* __restrict__ pair2, const float4* __restrict__ geom4,
    const unsigned short* __restrict__ attrb,
    const unsigned short* __restrict__ PD, const unsigned short* __restrict__ PS,
    const unsigned short* __restrict__ WT1r,
    const unsigned short* __restrict__ WT_e2,
    const unsigned short* __restrict__ WT_x1,
    const float* __restrict__ b_e2,
    const float* __restrict__ W_g,  const float* __restrict__ b_g,
    const float* __restrict__ b_x1, const float* __restrict__ W_x2,
    float* __restrict__ agg, float* __restrict__ dxv)
{
    __shared__ __align__(16) unsigned short T[2][32*TS];   // rbf-acc, then m2
    __shared__ int   s_dst[2][33];
    __shared__ float s_g[2][32];
    __shared__ float s_vec[2][96];

    const int wv   = threadIdx.x >> 6;
    const int lane = threadIdx.x & 63;
    const int quad = lane >> 4;
    const int l15  = lane & 15;
    const int e0   = (blockIdx.x * 2 + wv) * 32;

    unsigned short* Tw = &T[wv][0];

    // --- coalesced meta (lanes 0..31 own one edge each) ---
    int   sreg = 0, dreg = 0;
    float rxr = 0.f, ryr = 0.f, rzr = 0.f, rreg = 0.f;
    if (lane < 32) {
        int2  p = pair2[e0 + lane];
        float4 g = geom4[e0 + lane];
        sreg = p.x; dreg = p.y;
        rxr = g.x; ryr = g.y; rzr = g.z; rreg = g.w;
        s_dst[wv][lane] = dreg;
    }
    if (lane == 32) s_dst[wv][32] = -1;

    // --- epilogue constants hoisted to registers (fast L2 hits, issued early) ---
    float be2v[8], wgv8[8], bx1v[8], wx2v[8];
    #pragma unroll
    for (int t = 0; t < 8; ++t) {
        int col = t*16 + l15;
        be2v[t] = b_e2[col];
        wgv8[t] = W_g[col];
        bx1v[t] = b_x1[col];
        wx2v[t] = W_x2[col];
    }
    const float bg0 = b_g[0];

    const int   nd0 = __shfl(dreg, l15);
    const int   ns0 = __shfl(sreg, l15);
    const float rr0 = __shfl(rreg, l15);
    const int   nd1 = __shfl(dreg, 16 + l15);
    const int   ns1 = __shfl(sreg, 16 + l15);
    const float rr1 = __shfl(rreg, 16 + l15);

    // --- issue long-latency PD/PS gathers ---
    short8 pdv0[4], psv0[4], pdv1[4], psv1[4];
    #pragma unroll
    for (int kc = 0; kc < 4; ++kc) {
        pdv0[kc] = *(const short8*)(PD + (size_t)nd0*HID + kc*32 + quad*8);
        psv0[kc] = *(const short8*)(PS + (size_t)ns0*HID + kc*32 + quad*8);
        pdv1[kc] = *(const short8*)(PD + (size_t)nd1*HID + kc*32 + quad*8);
        psv1[kc] = *(const short8*)(PS + (size_t)ns1*HID + kc*32 + quad*8);
    }

    // rbf fragments (packed-pair converts); attr from sorted bf16 stream
    short8 ar0, ar1;
    {
        const float step  = 10.0f / 19.0f;
        const float coeff = -0.5f / (step*step);
        uintx4 u0, u1;
        #pragma unroll
        for (int jp = 0; jp < 4; ++jp) {
            float v[4];
            #pragma unroll
            for (int half = 0; half < 2; ++half) {
                float rr = half ? rr1 : rr0;
                int rowbase = e0 + (half ? 16 : 0) + l15;
                #pragma unroll
                for (int q = 0; q < 2; ++q) {
                    int col = quad*8 + jp*2 + q;
                    float val = 0.f;
                    if (col < NUM_G) {
                        float d = rr - step*(float)col;
                        val = __expf(coeff*d*d);
                    } else if (col < NUM_G+EF) {
                        val = bf2f(attrb[(size_t)rowbase*4 + (col-NUM_G)]);
                    }
                    v[half*2 + q] = val;
                }
            }
            u0[jp] = pk2(v[0], v[1]);
            u1[jp] = pk2(v[2], v[3]);
        }
        ar0 = __builtin_bit_cast(short8, u0);
        ar1 = __builtin_bit_cast(short8, u1);
    }

    floatx4 acc0[8], acc1[8];
    #pragma unroll
    for (int t = 0; t < 8; ++t) { acc0[t] = (floatx4){0,0,0,0}; acc1[t] = (floatx4){0,0,0,0}; }
    #pragma unroll
    for (int t = 0; t < 8; ++t) {
        short8 b = *(const short8*)(WT1r + (size_t)(t*16+l15)*32 + quad*8);
        acc0[t] = __builtin_amdgcn_mfma_f32_16x16x32_bf16(ar0, b, acc0[t], 0, 0, 0);
        acc1[t] = __builtin_amdgcn_mfma_f32_16x16x32_bf16(ar1, b, acc1[t], 0, 0, 0);
    }
    #pragma unroll
    for (int t = 0; t < 8; ++t) {
        int col = t*16 + l15;
        #pragma unroll
        for (int i = 0; i < 4; i += 2) {
            unsigned int u0 = pk2(acc0[t][i], acc0[t][i+1]);
            unsigned int u1 = pk2(acc1[t][i], acc1[t][i+1]);
            Tw[(quad*4+i)*TS + col]        = (unsigned short)u0;
            Tw[(quad*4+i+1)*TS + col]      = (unsigned short)(u0 >> 16);
            Tw[(16+quad*4+i)*TS + col]     = (unsigned short)u1;
            Tw[(16+quad*4+i+1)*TS + col]   = (unsigned short)(u1 >> 16);
        }
    }
    __builtin_amdgcn_wave_barrier();

    // layer-1 finalize: m1 = silu(PD[dst]+PS[src]+rbf)  (bias folded in PD)
    short8 a2[8];
    #pragma unroll
    for (int kc = 0; kc < 4; ++kc) {
        uintx4 rv0 = __builtin_bit_cast(uintx4, *(const short8*)(&Tw[l15*TS + kc*32 + quad*8]));
        uintx4 rv1 = __builtin_bit_cast(uintx4, *(const short8*)(&Tw[(16+l15)*TS + kc*32 + quad*8]));
        uintx4 pu0 = __builtin_bit_cast(uintx4, pdv0[kc]);
        uintx4 su0 = __builtin_bit_cast(uintx4, psv0[kc]);
        uintx4 pu1 = __builtin_bit_cast(uintx4, pdv1[kc]);
        uintx4 su1 = __builtin_bit_cast(uintx4, psv1[kc]);
        uintx4 o0, o1;
        #pragma unroll
        for (int w = 0; w < 4; ++w) {
            float2 p0 = up2(pu0[w]), s0 = up2(su0[w]), r0 = up2(rv0[w]);
            float2 p1 = up2(pu1[w]), s1 = up2(su1[w]), r1 = up2(rv1[w]);
            o0[w] = pk2(silu_f(p0.x + s0.x + r0.x), silu_f(p0.y + s0.y + r0.y));
            o1[w] = pk2(silu_f(p1.x + s1.x + r1.x), silu_f(p1.y + s1.y + r1.y));
        }
        a2[kc]   = __builtin_bit_cast(short8, o0);
        a2[4+kc] = __builtin_bit_cast(short8, o1);
    }
    __builtin_amdgcn_wave_barrier();

    // --- GEMM2: m2 = silu(m1 @ W_e2 + b), gate; B loaded once for both tiles ---
    #pragma unroll
    for (int t = 0; t < 8; ++t) { acc0[t] = (floatx4){0,0,0,0}; acc1[t] = (floatx4){0,0,0,0}; }
    #pragma unroll
    for (int kc = 0; kc < 4; ++kc) {
        #pragma unroll
        for (int t = 0; t < 8; ++t) {
            short8 b = *(const short8*)(WT_e2 + (size_t)(t*16+l15)*HID + kc*32 + quad*8);
            acc0[t] = __builtin_amdgcn_mfma_f32_16x16x32_bf16(a2[kc],   b, acc0[t], 0, 0, 0);
            acc1[t] = __builtin_amdgcn_mfma_f32_16x16x32_bf16(a2[4+kc], b, acc1[t], 0, 0, 0);
        }
    }
    {
        float gp0[4] = {0,0,0,0}, gp1[4] = {0,0,0,0};
        #pragma unroll
        for (int t = 0; t < 8; ++t) {
            int col = t*16 + l15;
            float bv = be2v[t];
            float wgv = wgv8[t];
            #pragma unroll
            for (int i = 0; i < 4; i += 2) {
                float m20a = silu_f(acc0[t][i]   + bv);
                float m20b = silu_f(acc0[t][i+1] + bv);
                float m21a = silu_f(acc1[t][i]   + bv);
                float m21b = silu_f(acc1[t][i+1] + bv);
                gp0[i] += m20a * wgv; gp0[i+1] += m20b * wgv;
                gp1[i] += m21a * wgv; gp1[i+1] += m21b * wgv;
                unsigned int u0 = pk2(m20a, m20b);
                unsigned int u1 = pk2(m21a, m21b);
                Tw[(quad*4+i)*TS + col]      = (unsigned short)u0;
                Tw[(quad*4+i+1)*TS + col]    = (unsigned short)(u0 >> 16);
                Tw[(16+quad*4+i)*TS + col]   = (unsigned short)u1;
                Tw[(16+quad*4+i+1)*TS + col] = (unsigned short)(u1 >> 16);
            }
        }
        #pragma unroll
        for (int i = 0; i < 4; ++i) {
            gp0[i] += __shfl_xor(gp0[i], 1); gp0[i] += __shfl_xor(gp0[i], 2);
            gp0[i] += __shfl_xor(gp0[i], 4); gp0[i] += __shfl_xor(gp0[i], 8);
            gp1[i] += __shfl_xor(gp1[i], 1); gp1[i] += __shfl_xor(gp1[i], 2);
            gp1[i] += __shfl_xor(gp1[i], 4); gp1[i] += __shfl_xor(gp1[i], 8);
        }
        if (l15 == 0) {
            #pragma unroll
            for (int i = 0; i < 4; ++i) {
                s_g[wv][quad*4 + i]      = sigm_f(gp0[i] + bg0);
                s_g[wv][16 + quad*4 + i] = sigm_f(gp1[i] + bg0);
            }
        }
    }
    __builtin_amdgcn_wave_barrier();

    // --- GEMM3: coord head (m2 from T, both tiles) ---
    #pragma unroll
    for (int kc = 0; kc < 4; ++kc) {
        a2[kc]   = *(const short8*)(&Tw[l15*TS + kc*32 + quad*8]);
        a2[4+kc] = *(const short8*)(&Tw[(16+l15)*TS + kc*32 + quad*8]);
    }
    #pragma unroll
    for (int t = 0; t < 8; ++t) { acc0[t] = (floatx4){0,0,0,0}; acc1[t] = (floatx4){0,0,0,0}; }
    #pragma unroll
    for (int kc = 0; kc < 4; ++kc) {
        #pragma unroll
        for (int t = 0; t < 8; ++t) {
            short8 b = *(const short8*)(WT_x1 + (size_t)(t*16+l15)*HID + kc*32 + quad*8);
            acc0[t] = __builtin_amdgcn_mfma_f32_16x16x32_bf16(a2[kc],   b, acc0[t], 0, 0, 0);
            acc1[t] = __builtin_amdgcn_mfma_f32_16x16x32_bf16(a2[4+kc], b, acc1[t], 0, 0, 0);
        }
    }
    {
        float cp0[4] = {0,0,0,0}, cp1[4] = {0,0,0,0};
        #pragma unroll
        for (int t = 0; t < 8; ++t) {
            float bv = bx1v[t];
            float wx = wx2v[t];
            #pragma unroll
            for (int i = 0; i < 4; ++i) {
                cp0[i] += silu_f(acc0[t][i] + bv) * wx;
                cp1[i] += silu_f(acc1[t][i] + bv) * wx;
            }
        }
        #pragma unroll
        for (int i = 0; i < 4; ++i) {
            cp0[i] += __shfl_xor(cp0[i], 1); cp0[i] += __shfl_xor(cp0[i], 2);
            cp0[i] += __shfl_xor(cp0[i], 4); cp0[i] += __shfl_xor(cp0[i], 8);
            cp1[i] += __shfl_xor(cp1[i], 1); cp1[i] += __shfl_xor(cp1[i], 2);
            cp1[i] += __shfl_xor(cp1[i], 4); cp1[i] += __shfl_xor(cp1[i], 8);
        }
        if (l15 < 3) {
            #pragma unroll
            for (int i = 0; i < 4; ++i) {
                int r0 = quad*4 + i;
                int r1 = 16 + quad*4 + i;
                float relc0 = (l15 == 0) ? __shfl(rxr, r0) : ((l15 == 1) ? __shfl(ryr, r0) : __shfl(rzr, r0));
                float relc1 = (l15 == 0) ? __shfl(rxr, r1) : ((l15 == 1) ? __shfl(ryr, r1) : __shfl(rzr, r1));
                float rv0 = __shfl(rreg, r0);
                float rv1 = __shfl(rreg, r1);
                s_vec[wv][r0*3 + l15] = relc0 * __builtin_amdgcn_rcpf(rv0 + 1.0f) * tanh_f(cp0[i]);
                s_vec[wv][r1*3 + l15] = relc1 * __builtin_amdgcn_rcpf(rv1 + 1.0f) * tanh_f(cp1[i]);
            }
        }
    }
    __builtin_amdgcn_wave_barrier();

    // --- scatters last ---
    {
        float am0 = 0.f, am1 = 0.f;
        #pragma unroll
        for (int r = 0; r < 32; ++r) {
            unsigned int pv = *(const unsigned int*)(&Tw[r*TS + lane*2]);
            float gr = s_g[wv][r];
            float2 f = up2(pv);
            am0 += f.x * gr;
            am1 += f.y * gr;
            int dr = s_dst[wv][r];
            if (dr != s_dst[wv][r+1]) {
                atomicAdd(&agg[(size_t)dr*HID + lane*2],     am0);
                atomicAdd(&agg[(size_t)dr*HID + lane*2 + 1], am1);
                am0 = 0.f; am1 = 0.f;
            }
        }
    }
    if (lane < 3) {
        float a = 0.f;
        #pragma unroll
        for (int r = 0; r < 32; ++r) {
            a += s_vec[wv][r*3 + lane];
            int dr = s_dst[wv][r];
            if (dr != s_dst[wv][r+1]) {
                atomicAdd(&dxv[(size_t)dr*3 + lane], a);
                a = 0.f;
            }
        }
    }
}

// ---- node kernel: ONE WAVE per block, 16 nodes ----
__global__ __launch_bounds__(64, 4) void egnn_node_mfma(
    const float* __restrict__ h, const float* __restrict__ x,
    const int* __restrict__ mask,
    const float* __restrict__ agg, const float* __restrict__ dxv,
    const unsigned short* __restrict__ WT_n1, const float* __restrict__ b_n1,
    const unsigned short* __restrict__ WT_n2, const float* __restrict__ b_n2,
    float* __restrict__ h_out, float* __restrict__ x_out)
{
    __shared__ __align__(16) unsigned short T[16*TS];

    const int lane = threadIdx.x;
    const int quad = lane >> 4;
    const int l15  = lane & 15;
    const int n0   = blockIdx.x * 16;

    if (lane < 48) {
        int r = lane / 3, c = lane % 3;
        int n = n0 + r;
        x_out[n*3 + c] = x[n*3 + c] + dxv[n*3 + c] * (float)mask[n];
    }

    const int node = n0 + l15;
    short8 a1[8];
    #pragma unroll
    for (int kc = 0; kc < 4; ++kc) {
        const float* p = agg + (size_t)node*HID + kc*32 + quad*8;
        float4 f0 = *(const float4*)(p);
        float4 f1 = *(const float4*)(p + 4);
        uintx4 u;
        u[0] = pk2(f0.x, f0.y); u[1] = pk2(f0.z, f0.w);
        u[2] = pk2(f1.x, f1.y); u[3] = pk2(f1.z, f1.w);
        a1[kc] = __builtin_bit_cast(short8, u);
    }
    #pragma unroll
    for (int kc = 0; kc < 4; ++kc) {
        const float* p = h + (size_t)node*HID + kc*32 + quad*8;
        float4 f0 = *(const float4*)(p);
        float4 f1 = *(const float4*)(p + 4);
        uintx4 u;
        u[0] = pk2(f0.x, f0.y); u[1] = pk2(f0.z, f0.w);
        u[2] = pk2(f1.x, f1.y); u[3] = pk2(f1.z, f1.w);
        a1[4+kc] = __builtin_bit_cast(short8, u);
    }

    floatx4 acc[8];
    #pragma unroll
    for (int t = 0; t < 8; ++t) acc[t] = (floatx4){0,0,0,0};
    #pragma unroll
    for (int kc = 0; kc < 8; ++kc) {
        #pragma unroll
        for (int t = 0; t < 8; ++t) {
            short8 b = *(const short8*)(WT_n1 + (size_t)(t*16+l15)*KN1 + kc*32 + quad*8);
            acc[t] = __builtin_amdgcn_mfma_f32_16x16x32_bf16(a1[kc], b, acc[t], 0, 0, 0);
        }
    }
    #pragma unroll
    for (int t = 0; t < 8; ++t) {
        int col = t*16 + l15;
        float bv = b_n1[col];
        #pragma unroll
        for (int i = 0; i < 4; i += 2) {
            unsigned int u = pk2(silu_f(acc[t][i] + bv), silu_f(acc[t][i+1] + bv));
            T[(quad*4+i)*TS + col]   = (unsigned short)u;
            T[(quad*4+i+1)*TS + col] = (unsigned short)(u >> 16);
        }
    }
    __builtin_amdgcn_wave_barrier();

    short8 a2[4];
    #pragma unroll
    for (int kc = 0; kc < 4; ++kc)
        a2[kc] = *(const short8*)(&T[l15*TS + kc*32 + quad*8]);
    #pragma unroll
    for (int t = 0; t < 8; ++t) acc[t] = (floatx4){0,0,0,0};
    #pragma unroll
    for (int kc = 0; kc < 4; ++kc) {
        #pragma unroll
        for (int t = 0; t < 8; ++t) {
            short8 b = *(const short8*)(WT_n2 + (size_t)(t*16+l15)*HID + kc*32 + quad*8);
            acc[t] = __builtin_amdgcn_mfma_f32_16x16x32_bf16(a2[kc], b, acc[t], 0, 0, 0);
        }
    }
    #pragma unroll
    for (int t = 0; t < 8; ++t) {
        int col = t*16 + l15;
        float bv = b_n2[col];
        #pragma unroll
        for (int i = 0; i < 4; ++i) {
            int n = n0 + quad*4 + i;
            h_out[(size_t)n*HID + col] = h[(size_t)n*HID + col] + acc[t][i] + bv;
        }
    }
}

extern "C" void kernel_launch(void* const* d_in, const int* in_sizes, int n_in,
                              void* d_out, int out_size, void* d_ws, size_t ws_size,
                              hipStream_t stream) {
    const float* h          = (const float*)d_in[0];
    const float* x          = (const float*)d_in[1];
    const float* edge_attr  = (const float*)d_in[2];
    const int*   edge_index = (const int*)  d_in[3];
    const int*   mask       = (const int*)  d_in[4];
    const float* W_e1 = (const float*)d_in[5];
    const float* b_e1 = (const float*)d_in[6];
    const float* W_e2 = (const float*)d_in[7];
    const float* b_e2 = (const float*)d_in[8];
    const float* W_g  = (const float*)d_in[9];
    const float* b_g  = (const float*)d_in[10];
    const float* W_n1 = (const float*)d_in[11];
    const float* b_n1 = (const float*)d_in[12];
    const float* W_n2 = (const float*)d_in[13];
    const float* b_n2 = (const float*)d_in[14];
    const float* W_x1 = (const float*)d_in[15];
    const float* b_x1 = (const float*)d_in[16];
    const float* W_x2 = (const float*)d_in[17];

    char* ws = (char*)d_ws;
    float* agg = (float*)ws;                       ws += (size_t)NN*HID*4;
    float* dxv = (float*)ws;                       ws += (size_t)NN*3*4;
    int*   counts = (int*)ws;                      ws += (size_t)NN*4;
    int*   cursor = (int*)ws;                      ws += (size_t)NN*4;
    int2*  pair2  = (int2*)ws;                     ws += (size_t)NE*8;
    float4* geom4 = (float4*)ws;                   ws += (size_t)NE*16;
    unsigned short* attrb = (unsigned short*)ws;   ws += (size_t)NE*4*2;
    unsigned short* PD    = (unsigned short*)ws;   ws += (size_t)NN*HID*2;
    unsigned short* PS    = (unsigned short*)ws;   ws += (size_t)NN*HID*2;
    unsigned short* WT1d  = (unsigned short*)ws;   ws += (size_t)HID*HID*2;
    unsigned short* WT1s  = (unsigned short*)ws;   ws += (size_t)HID*HID*2;
    unsigned short* WT1r  = (unsigned short*)ws;   ws += (size_t)HID*32*2;
    unsigned short* WT_e2 = (unsigned short*)ws;   ws += (size_t)HID*HID*2;
    unsigned short* WT_x1 = (unsigned short*)ws;   ws += (size_t)HID*HID*2;
    unsigned short* WT_n1 = (unsigned short*)ws;   ws += (size_t)HID*KN1*2;
    unsigned short* WT_n2 = (unsigned short*)ws;   ws += (size_t)HID*HID*2;

    hipMemsetAsync(counts, 0, (size_t)NN*sizeof(int), stream);

    prep_all_kernel<<<128 + NE/320 + A_ZBLK, 320, 0, stream>>>(
        W_e1, W_e2, W_x1, W_n1, W_n2,
        WT1d, WT1s, WT1r, WT_e2, WT_x1, WT_n1, WT_n2,
        edge_index, counts, (float4*)agg);

    scan_kernel<<<1, 1024, 0, stream>>>(counts, cursor);

    build_pd_kernel<<<PD_BLOCKS + NE/256, 256, 0, stream>>>(
        edge_index, x, edge_attr, cursor, pair2, geom4, attrb,
        h, b_e1, WT1d, WT1s, PD, PS);

    egnn_edge_mfma<<<NE/64, 128, 0, stream>>>(
        pair2, geom4, attrb, PD, PS, WT1r, WT_e2, WT_x1,
        b_e2, W_g, b_g, b_x1, W_x2, agg, dxv);

    float* h_out = (float*)d_out;
    float* x_out = h_out + (size_t)NN*HID;

    egnn_node_mfma<<<NN/16, 64, 0, stream>>>(
        h, x, mask, agg, dxv, WT_n1, b_n1, WT_n2, b_n2, h_out, x_out);
}

// Round 13
// 510.630 us; speedup vs baseline: 1.0265x; 1.0265x over previous
//
#include <hip/hip_runtime.h>
#include <hip/hip_bf16.h>
#include <math.h>

#define HID 128
#define NUM_G 20
#define EF 4
#define NN 20000
#define NE 640000
#define KN1 256           // node GEMM1 K
#define TS 136            // LDS stride (bf16): 272B rows -> near-conflict-free

typedef __attribute__((ext_vector_type(8))) short short8;
typedef __attribute__((ext_vector_type(4))) short short4v;
typedef __attribute__((ext_vector_type(4))) float floatx4;
typedef __attribute__((ext_vector_type(4))) unsigned int uintx4;

__device__ __forceinline__ float silu_f(float v){
    return v * __builtin_amdgcn_rcpf(1.0f + __expf(-v));
}
__device__ __forceinline__ float sigm_f(float v){
    return __builtin_amdgcn_rcpf(1.0f + __expf(-v));
}
__device__ __forceinline__ float tanh_f(float v){
    return 1.0f - 2.0f * __builtin_amdgcn_rcpf(1.0f + __expf(2.0f * v));
}
__device__ __forceinline__ unsigned short f2bf(float v){
    unsigned int u = __float_as_uint(v);
    u = (u + 0x7fffu + ((u >> 16) & 1u)) >> 16;
    return (unsigned short)u;
}
__device__ __forceinline__ float bf2f(unsigned short u){
    return __uint_as_float(((unsigned int)u) << 16);
}
__device__ __forceinline__ unsigned int pk2(float a, float b){
    __hip_bfloat162 h = __float22bfloat162_rn(make_float2(a, b));
    return *(unsigned int*)&h;
}
__device__ __forceinline__ float2 up2(unsigned int u){
    __hip_bfloat162 h = *(__hip_bfloat162*)&u;
    return __bfloat1622float2(h);
}

// ---- fused: weight transpose/bf16 (blocks 0..127) ∥ dst histogram (blocks 128+) ----
__global__ __launch_bounds__(320) void prep_hist_kernel(
    const float* __restrict__ W_e1, const float* __restrict__ W_e2,
    const float* __restrict__ W_x1, const float* __restrict__ W_n1,
    const float* __restrict__ W_n2,
    unsigned short* __restrict__ WT1d, unsigned short* __restrict__ WT1s,
    unsigned short* __restrict__ WT1r,
    unsigned short* __restrict__ WT_e2, unsigned short* __restrict__ WT_x1,
    unsigned short* __restrict__ WT_n1, unsigned short* __restrict__ WT_n2,
    const int* __restrict__ edge_index, int* __restrict__ counts)
{
    int t = threadIdx.x;
    if (blockIdx.x < 128) {
        int n = blockIdx.x;
        if (t < HID) {
            WT1d[n*HID + t] = f2bf(W_e1[t*HID + n]);
            WT1s[n*HID + t] = f2bf(W_e1[(HID+t)*HID + n]);
            WT_e2[n*HID + t] = f2bf(W_e2[t*HID + n]);
            WT_x1[n*HID + t] = f2bf(W_x1[t*HID + n]);
            WT_n2[n*HID + t] = f2bf(W_n2[t*HID + n]);
        }
        if (t < 32) WT1r[n*32 + t] = (t < NUM_G+EF) ? f2bf(W_e1[(256+t)*HID + n]) : (unsigned short)0;
        if (t < KN1) WT_n1[n*KN1 + t] = f2bf(W_n1[t*HID + n]);
    } else {
        int e = (blockIdx.x - 128) * 320 + t;   // NE = 2000*320
        atomicAdd(&counts[edge_index[NE + e]], 1);
    }
}

__global__ __launch_bounds__(1024) void scan_kernel(
    const int* __restrict__ counts, int* __restrict__ cursor)
{
    __shared__ int part[1024];
    const int t = threadIdx.x;
    const int CH = (NN + 1023) / 1024;   // 20
    int base = t * CH;
    int s = 0;
    for (int i = 0; i < CH; ++i) { int idx = base + i; if (idx < NN) s += counts[idx]; }
    part[t] = s; __syncthreads();
    for (int off = 1; off < 1024; off <<= 1) {
        int v = (t >= off) ? part[t - off] : 0;
        __syncthreads();
        part[t] += v;
        __syncthreads();
    }
    int run = (t == 0) ? 0 : part[t - 1];
    for (int i = 0; i < CH; ++i) {
        int idx = base + i;
        if (idx < NN) { cursor[idx] = run; run += counts[idx]; }
    }
}

// ---- Kernel C: pd (blocks 0..312, 4 waves x 16 nodes) ∥ build (blocks 313+) ----
#define PD_BLOCKS ((NN + 63) / 64)    // 313
__global__ __launch_bounds__(256) void build_pd_kernel(
    const int* __restrict__ edge_index, const float* __restrict__ x,
    const float* __restrict__ edge_attr, int* __restrict__ cursor,
    int2* __restrict__ pair2, float4* __restrict__ geom4,
    unsigned short* __restrict__ attrb,
    const float* __restrict__ h, const float* __restrict__ b_e1,
    const unsigned short* __restrict__ WT1d, const unsigned short* __restrict__ WT1s,
    unsigned short* __restrict__ PD, unsigned short* __restrict__ PS)
{
    __shared__ __align__(16) unsigned short T[4][16*TS];

    if (blockIdx.x >= PD_BLOCKS) {
        // ---- build part ----
        int e = (blockIdx.x - PD_BLOCKS) * 256 + threadIdx.x;
        int s = edge_index[e];
        int d = edge_index[NE + e];
        int pos = atomicAdd(&cursor[d], 1);
        float rx = x[d*3+0] - x[s*3+0];
        float ry = x[d*3+1] - x[s*3+1];
        float rz = x[d*3+2] - x[s*3+2];
        float r  = sqrtf(rx*rx + ry*ry + rz*rz + 1e-8f);
        pair2[pos] = make_int2(s, d);
        geom4[pos] = make_float4(rx, ry, rz, r);
        short4v a;
        #pragma unroll
        for (int j = 0; j < 4; ++j) a[j] = (short)f2bf(edge_attr[(size_t)e*EF + j]);
        *(short4v*)(attrb + (size_t)pos*4) = a;
        return;
    }

    // ---- pd part: 4 autonomous waves, 16 nodes each ----
    const int wv   = threadIdx.x >> 6;
    const int lane = threadIdx.x & 63;
    const int quad = lane >> 4;
    const int l15  = lane & 15;
    int node = blockIdx.x * 64 + wv * 16 + l15;
    if (node >= NN) node = NN - 1;     // duplicate-write guard (same data)
    unsigned short* Tw = &T[wv][0];

    short8 ah[4];
    #pragma unroll
    for (int kc = 0; kc < 4; ++kc) {
        const float* p = h + (size_t)node*HID + kc*32 + quad*8;
        float4 f0 = *(const float4*)(p);
        float4 f1 = *(const float4*)(p + 4);
        uintx4 u;
        u[0] = pk2(f0.x, f0.y); u[1] = pk2(f0.z, f0.w);
        u[2] = pk2(f1.x, f1.y); u[3] = pk2(f1.z, f1.w);
        ah[kc] = __builtin_bit_cast(short8, u);
    }

    floatx4 ad[8], as[8];
    #pragma unroll
    for (int t = 0; t < 8; ++t) { ad[t] = (floatx4){0,0,0,0}; as[t] = (floatx4){0,0,0,0}; }
    #pragma unroll
    for (int kc = 0; kc < 4; ++kc) {
        #pragma unroll
        for (int t = 0; t < 8; ++t) {
            short8 bd = *(const short8*)(WT1d + (size_t)(t*16+l15)*HID + kc*32 + quad*8);
            short8 bs = *(const short8*)(WT1s + (size_t)(t*16+l15)*HID + kc*32 + quad*8);
            ad[t] = __builtin_amdgcn_mfma_f32_16x16x32_bf16(ah[kc], bd, ad[t], 0, 0, 0);
            as[t] = __builtin_amdgcn_mfma_f32_16x16x32_bf16(ah[kc], bs, as[t], 0, 0, 0);
        }
    }
    #pragma unroll
    for (int t = 0; t < 8; ++t) {
        int col = t*16 + l15;
        float bv = b_e1[col];
        #pragma unroll
        for (int i = 0; i < 4; ++i)
            Tw[(quad*4+i)*TS + col] = f2bf(ad[t][i] + bv);
    }
    __builtin_amdgcn_wave_barrier();
    #pragma unroll
    for (int kc = 0; kc < 4; ++kc)
        *(short8*)(PD + (size_t)node*HID + kc*32 + quad*8) =
            *(const short8*)(&Tw[l15*TS + kc*32 + quad*8]);
    __builtin_amdgcn_wave_barrier();
    #pragma unroll
    for (int t = 0; t < 8; ++t) {
        int col = t*16 + l15;
        #pragma unroll
        for (int i = 0; i < 4; ++i)
            Tw[(quad*4+i)*TS + col] = f2bf(as[t][i]);
    }
    __builtin_amdgcn_wave_barrier();
    #pragma unroll
    for (int kc = 0; kc < 4; ++kc)
        *(short8*)(PS + (size_t)node*HID + kc*32 + quad*8) =
            *(const short8*)(&Tw[l15*TS + kc*32 + quad*8]);
}

// ---- edge kernel: 128 threads = 2 autonomous waves, 32 sorted edges/wave (R11 body).
// launch_bounds (128,3): arg=4 clamps VGPR to 64 -> spill cliff (R6/R10); arg=3 ok.
// Epilogue constants intentionally NOT hoisted: early hoist delays PD/PS in vmcnt FIFO (R12).
__global__ __launch_bounds__(128, 3) void egnn_edge_mfma(
    const int2* __restrict__ pair2, const float4* __restrict__ geom4,
    const unsigned short* __restrict__ attrb,
    const unsigned short* __restrict__ PD, const unsigned short* __restrict__ PS,
    const unsigned short* __restrict__ WT1r,
    const unsigned short* __restrict__ WT_e2,
    const unsigned short* __restrict__ WT_x1,
    const float* __restrict__ b_e2,
    const float* __restrict__ W_g,  const float* __restrict__ b_g,
    const float* __restrict__ b_x1, const float* __restrict__ W_x2,
    float* __restrict__ agg, float* __restrict__ dxv)
{
    __shared__ __align__(16) unsigned short T[2][32*TS];   // rbf-acc, then m2
    __shared__ int   s_dst[2][33];
    __shared__ float s_g[2][32];
    __shared__ float s_vec[2][96];

    const int wv   = threadIdx.x >> 6;
    const int lane = threadIdx.x & 63;
    const int quad = lane >> 4;
    const int l15  = lane & 15;
    const int e0   = (blockIdx.x * 2 + wv) * 32;

    unsigned short* Tw = &T[wv][0];

    // --- coalesced meta (lanes 0..31 own one edge each) ---
    int   sreg = 0, dreg = 0;
    float rxr = 0.f, ryr = 0.f, rzr = 0.f, rreg = 0.f;
    if (lane < 32) {
        int2  p = pair2[e0 + lane];
        float4 g = geom4[e0 + lane];
        sreg = p.x; dreg = p.y;
        rxr = g.x; ryr = g.y; rzr = g.z; rreg = g.w;
        s_dst[wv][lane] = dreg;
    }
    if (lane == 32) s_dst[wv][32] = -1;

    const int   nd0 = __shfl(dreg, l15);
    const int   ns0 = __shfl(sreg, l15);
    const float rr0 = __shfl(rreg, l15);
    const int   nd1 = __shfl(dreg, 16 + l15);
    const int   ns1 = __shfl(sreg, 16 + l15);
    const float rr1 = __shfl(rreg, 16 + l15);

    // --- issue long-latency PD/PS gathers first ---
    short8 pdv0[4], psv0[4], pdv1[4], psv1[4];
    #pragma unroll
    for (int kc = 0; kc < 4; ++kc) {
        pdv0[kc] = *(const short8*)(PD + (size_t)nd0*HID + kc*32 + quad*8);
        psv0[kc] = *(const short8*)(PS + (size_t)ns0*HID + kc*32 + quad*8);
        pdv1[kc] = *(const short8*)(PD + (size_t)nd1*HID + kc*32 + quad*8);
        psv1[kc] = *(const short8*)(PS + (size_t)ns1*HID + kc*32 + quad*8);
    }

    // rbf fragments (packed-pair converts); attr from sorted bf16 stream
    short8 ar0, ar1;
    {
        const float step  = 10.0f / 19.0f;
        const float coeff = -0.5f / (step*step);
        uintx4 u0, u1;
        #pragma unroll
        for (int jp = 0; jp < 4; ++jp) {
            float v[4];
            #pragma unroll
            for (int half = 0; half < 2; ++half) {
                float rr = half ? rr1 : rr0;
                int rowbase = e0 + (half ? 16 : 0) + l15;
                #pragma unroll
                for (int q = 0; q < 2; ++q) {
                    int col = quad*8 + jp*2 + q;
                    float val = 0.f;
                    if (col < NUM_G) {
                        float d = rr - step*(float)col;
                        val = __expf(coeff*d*d);
                    } else if (col < NUM_G+EF) {
                        val = bf2f(attrb[(size_t)rowbase*4 + (col-NUM_G)]);
                    }
                    v[half*2 + q] = val;
                }
            }
            u0[jp] = pk2(v[0], v[1]);
            u1[jp] = pk2(v[2], v[3]);
        }
        ar0 = __builtin_bit_cast(short8, u0);
        ar1 = __builtin_bit_cast(short8, u1);
    }

    floatx4 acc0[8], acc1[8];
    #pragma unroll
    for (int t = 0; t < 8; ++t) { acc0[t] = (floatx4){0,0,0,0}; acc1[t] = (floatx4){0,0,0,0}; }
    #pragma unroll
    for (int t = 0; t < 8; ++t) {
        short8 b = *(const short8*)(WT1r + (size_t)(t*16+l15)*32 + quad*8);
        acc0[t] = __builtin_amdgcn_mfma_f32_16x16x32_bf16(ar0, b, acc0[t], 0, 0, 0);
        acc1[t] = __builtin_amdgcn_mfma_f32_16x16x32_bf16(ar1, b, acc1[t], 0, 0, 0);
    }
    #pragma unroll
    for (int t = 0; t < 8; ++t) {
        int col = t*16 + l15;
        #pragma unroll
        for (int i = 0; i < 4; i += 2) {
            unsigned int u0 = pk2(acc0[t][i], acc0[t][i+1]);
            unsigned int u1 = pk2(acc1[t][i], acc1[t][i+1]);
            Tw[(quad*4+i)*TS + col]        = (unsigned short)u0;
            Tw[(quad*4+i+1)*TS + col]      = (unsigned short)(u0 >> 16);
            Tw[(16+quad*4+i)*TS + col]     = (unsigned short)u1;
            Tw[(16+quad*4+i+1)*TS + col]   = (unsigned short)(u1 >> 16);
        }
    }
    __builtin_amdgcn_wave_barrier();

    // layer-1 finalize: m1 = silu(PD[dst]+PS[src]+rbf)  (bias folded in PD)
    short8 a2[8];
    #pragma unroll
    for (int kc = 0; kc < 4; ++kc) {
        uintx4 rv0 = __builtin_bit_cast(uintx4, *(const short8*)(&Tw[l15*TS + kc*32 + quad*8]));
        uintx4 rv1 = __builtin_bit_cast(uintx4, *(const short8*)(&Tw[(16+l15)*TS + kc*32 + quad*8]));
        uintx4 pu0 = __builtin_bit_cast(uintx4, pdv0[kc]);
        uintx4 su0 = __builtin_bit_cast(uintx4, psv0[kc]);
        uintx4 pu1 = __builtin_bit_cast(uintx4, pdv1[kc]);
        uintx4 su1 = __builtin_bit_cast(uintx4, psv1[kc]);
        uintx4 o0, o1;
        #pragma unroll
        for (int w = 0; w < 4; ++w) {
            float2 p0 = up2(pu0[w]), s0 = up2(su0[w]), r0 = up2(rv0[w]);
            float2 p1 = up2(pu1[w]), s1 = up2(su1[w]), r1 = up2(rv1[w]);
            o0[w] = pk2(silu_f(p0.x + s0.x + r0.x), silu_f(p0.y + s0.y + r0.y));
            o1[w] = pk2(silu_f(p1.x + s1.x + r1.x), silu_f(p1.y + s1.y + r1.y));
        }
        a2[kc]   = __builtin_bit_cast(short8, o0);
        a2[4+kc] = __builtin_bit_cast(short8, o1);
    }
    __builtin_amdgcn_wave_barrier();

    // --- GEMM2: m2 = silu(m1 @ W_e2 + b), gate; B loaded once for both tiles ---
    #pragma unroll
    for (int t = 0; t < 8; ++t) { acc0[t] = (floatx4){0,0,0,0}; acc1[t] = (floatx4){0,0,0,0}; }
    #pragma unroll
    for (int kc = 0; kc < 4; ++kc) {
        #pragma unroll
        for (int t = 0; t < 8; ++t) {
            short8 b = *(const short8*)(WT_e2 + (size_t)(t*16+l15)*HID + kc*32 + quad*8);
            acc0[t] = __builtin_amdgcn_mfma_f32_16x16x32_bf16(a2[kc],   b, acc0[t], 0, 0, 0);
            acc1[t] = __builtin_amdgcn_mfma_f32_16x16x32_bf16(a2[4+kc], b, acc1[t], 0, 0, 0);
        }
    }
    {
        float gp0[4] = {0,0,0,0}, gp1[4] = {0,0,0,0};
        #pragma unroll
        for (int t = 0; t < 8; ++t) {
            int col = t*16 + l15;
            float bv = b_e2[col];
            float wgv = W_g[col];
            #pragma unroll
            for (int i = 0; i < 4; i += 2) {
                float m20a = silu_f(acc0[t][i]   + bv);
                float m20b = silu_f(acc0[t][i+1] + bv);
                float m21a = silu_f(acc1[t][i]   + bv);
                float m21b = silu_f(acc1[t][i+1] + bv);
                gp0[i] += m20a * wgv; gp0[i+1] += m20b * wgv;
                gp1[i] += m21a * wgv; gp1[i+1] += m21b * wgv;
                unsigned int u0 = pk2(m20a, m20b);
                unsigned int u1 = pk2(m21a, m21b);
                Tw[(quad*4+i)*TS + col]      = (unsigned short)u0;
                Tw[(quad*4+i+1)*TS + col]    = (unsigned short)(u0 >> 16);
                Tw[(16+quad*4+i)*TS + col]   = (unsigned short)u1;
                Tw[(16+quad*4+i+1)*TS + col] = (unsigned short)(u1 >> 16);
            }
        }
        const float bg0 = b_g[0];
        #pragma unroll
        for (int i = 0; i < 4; ++i) {
            gp0[i] += __shfl_xor(gp0[i], 1); gp0[i] += __shfl_xor(gp0[i], 2);
            gp0[i] += __shfl_xor(gp0[i], 4); gp0[i] += __shfl_xor(gp0[i], 8);
            gp1[i] += __shfl_xor(gp1[i], 1); gp1[i] += __shfl_xor(gp1[i], 2);
            gp1[i] += __shfl_xor(gp1[i], 4); gp1[i] += __shfl_xor(gp1[i], 8);
        }
        if (l15 == 0) {
            #pragma unroll
            for (int i = 0; i < 4; ++i) {
                s_g[wv][quad*4 + i]      = sigm_f(gp0[i] + bg0);
                s_g[wv][16 + quad*4 + i] = sigm_f(gp1[i] + bg0);
            }
        }
    }
    __builtin_amdgcn_wave_barrier();

    // --- GEMM3: coord head (m2 from T, both tiles) ---
    #pragma unroll
    for (int kc = 0; kc < 4; ++kc) {
        a2[kc]   = *(const short8*)(&Tw[l15*TS + kc*32 + quad*8]);
        a2[4+kc] = *(const short8*)(&Tw[(16+l15)*TS + kc*32 + quad*8]);
    }
    #pragma unroll
    for (int t = 0; t < 8; ++t) { acc0[t] = (floatx4){0,0,0,0}; acc1[t] = (floatx4){0,0,0,0}; }
    #pragma unroll
    for (int kc = 0; kc < 4; ++kc) {
        #pragma unroll
        for (int t = 0; t < 8; ++t) {
            short8 b = *(const short8*)(WT_x1 + (size_t)(t*16+l15)*HID + kc*32 + quad*8);
            acc0[t] = __builtin_amdgcn_mfma_f32_16x16x32_bf16(a2[kc],   b, acc0[t], 0, 0, 0);
            acc1[t] = __builtin_amdgcn_mfma_f32_16x16x32_bf16(a2[4+kc], b, acc1[t], 0, 0, 0);
        }
    }
    {
        float cp0[4] = {0,0,0,0}, cp1[4] = {0,0,0,0};
        #pragma unroll
        for (int t = 0; t < 8; ++t) {
            int col = t*16 + l15;
            float bv = b_x1[col];
            float wx = W_x2[col];
            #pragma unroll
            for (int i = 0; i < 4; ++i) {
                cp0[i] += silu_f(acc0[t][i] + bv) * wx;
                cp1[i] += silu_f(acc1[t][i] + bv) * wx;
            }
        }
        #pragma unroll
        for (int i = 0; i < 4; ++i) {
            cp0[i] += __shfl_xor(cp0[i], 1); cp0[i] += __shfl_xor(cp0[i], 2);
            cp0[i] += __shfl_xor(cp0[i], 4); cp0[i] += __shfl_xor(cp0[i], 8);
            cp1[i] += __shfl_xor(cp1[i], 1); cp1[i] += __shfl_xor(cp1[i], 2);
            cp1[i] += __shfl_xor(cp1[i], 4); cp1[i] += __shfl_xor(cp1[i], 8);
        }
        if (l15 < 3) {
            #pragma unroll
            for (int i = 0; i < 4; ++i) {
                int r0 = quad*4 + i;
                int r1 = 16 + quad*4 + i;
                float relc0 = (l15 == 0) ? __shfl(rxr, r0) : ((l15 == 1) ? __shfl(ryr, r0) : __shfl(rzr, r0));
                float relc1 = (l15 == 0) ? __shfl(rxr, r1) : ((l15 == 1) ? __shfl(ryr, r1) : __shfl(rzr, r1));
                float rv0 = __shfl(rreg, r0);
                float rv1 = __shfl(rreg, r1);
                s_vec[wv][r0*3 + l15] = relc0 * __builtin_amdgcn_rcpf(rv0 + 1.0f) * tanh_f(cp0[i]);
                s_vec[wv][r1*3 + l15] = relc1 * __builtin_amdgcn_rcpf(rv1 + 1.0f) * tanh_f(cp1[i]);
            }
        }
    }
    __builtin_amdgcn_wave_barrier();

    // --- scatters last ---
    {
        float am0 = 0.f, am1 = 0.f;
        #pragma unroll
        for (int r = 0; r < 32; ++r) {
            unsigned int pv = *(const unsigned int*)(&Tw[r*TS + lane*2]);
            float gr = s_g[wv][r];
            float2 f = up2(pv);
            am0 += f.x * gr;
            am1 += f.y * gr;
            int dr = s_dst[wv][r];
            if (dr != s_dst[wv][r+1]) {
                atomicAdd(&agg[(size_t)dr*HID + lane*2],     am0);
                atomicAdd(&agg[(size_t)dr*HID + lane*2 + 1], am1);
                am0 = 0.f; am1 = 0.f;
            }
        }
    }
    if (lane < 3) {
        float a = 0.f;
        #pragma unroll
        for (int r = 0; r < 32; ++r) {
            a += s_vec[wv][r*3 + lane];
            int dr = s_dst[wv][r];
            if (dr != s_dst[wv][r+1]) {
                atomicAdd(&dxv[(size_t)dr*3 + lane], a);
                a = 0.f;
            }
        }
    }
}

// ---- node kernel: ONE WAVE per block, 16 nodes ----
__global__ __launch_bounds__(64, 4) void egnn_node_mfma(
    const float* __restrict__ h, const float* __restrict__ x,
    const int* __restrict__ mask,
    const float* __restrict__ agg, const float* __restrict__ dxv,
    const unsigned short* __restrict__ WT_n1, const float* __restrict__ b_n1,
    const unsigned short* __restrict__ WT_n2, const float* __restrict__ b_n2,
    float* __restrict__ h_out, float* __restrict__ x_out)
{
    __shared__ __align__(16) unsigned short T[16*TS];

    const int lane = threadIdx.x;
    const int quad = lane >> 4;
    const int l15  = lane & 15;
    const int n0   = blockIdx.x * 16;

    if (lane < 48) {
        int r = lane / 3, c = lane % 3;
        int n = n0 + r;
        x_out[n*3 + c] = x[n*3 + c] + dxv[n*3 + c] * (float)mask[n];
    }

    const int node = n0 + l15;
    short8 a1[8];
    #pragma unroll
    for (int kc = 0; kc < 4; ++kc) {
        const float* p = agg + (size_t)node*HID + kc*32 + quad*8;
        float4 f0 = *(const float4*)(p);
        float4 f1 = *(const float4*)(p + 4);
        uintx4 u;
        u[0] = pk2(f0.x, f0.y); u[1] = pk2(f0.z, f0.w);
        u[2] = pk2(f1.x, f1.y); u[3] = pk2(f1.z, f1.w);
        a1[kc] = __builtin_bit_cast(short8, u);
    }
    #pragma unroll
    for (int kc = 0; kc < 4; ++kc) {
        const float* p = h + (size_t)node*HID + kc*32 + quad*8;
        float4 f0 = *(const float4*)(p);
        float4 f1 = *(const float4*)(p + 4);
        uintx4 u;
        u[0] = pk2(f0.x, f0.y); u[1] = pk2(f0.z, f0.w);
        u[2] = pk2(f1.x, f1.y); u[3] = pk2(f1.z, f1.w);
        a1[4+kc] = __builtin_bit_cast(short8, u);
    }

    floatx4 acc[8];
    #pragma unroll
    for (int t = 0; t < 8; ++t) acc[t] = (floatx4){0,0,0,0};
    #pragma unroll
    for (int kc = 0; kc < 8; ++kc) {
        #pragma unroll
        for (int t = 0; t < 8; ++t) {
            short8 b = *(const short8*)(WT_n1 + (size_t)(t*16+l15)*KN1 + kc*32 + quad*8);
            acc[t] = __builtin_amdgcn_mfma_f32_16x16x32_bf16(a1[kc], b, acc[t], 0, 0, 0);
        }
    }
    #pragma unroll
    for (int t = 0; t < 8; ++t) {
        int col = t*16 + l15;
        float bv = b_n1[col];
        #pragma unroll
        for (int i = 0; i < 4; i += 2) {
            unsigned int u = pk2(silu_f(acc[t][i] + bv), silu_f(acc[t][i+1] + bv));
            T[(quad*4+i)*TS + col]   = (unsigned short)u;
            T[(quad*4+i+1)*TS + col] = (unsigned short)(u >> 16);
        }
    }
    __builtin_amdgcn_wave_barrier();

    short8 a2[4];
    #pragma unroll
    for (int kc = 0; kc < 4; ++kc)
        a2[kc] = *(const short8*)(&T[l15*TS + kc*32 + quad*8]);
    #pragma unroll
    for (int t = 0; t < 8; ++t) acc[t] = (floatx4){0,0,0,0};
    #pragma unroll
    for (int kc = 0; kc < 4; ++kc) {
        #pragma unroll
        for (int t = 0; t < 8; ++t) {
            short8 b = *(const short8*)(WT_n2 + (size_t)(t*16+l15)*HID + kc*32 + quad*8);
            acc[t] = __builtin_amdgcn_mfma_f32_16x16x32_bf16(a2[kc], b, acc[t], 0, 0, 0);
        }
    }
    #pragma unroll
    for (int t = 0; t < 8; ++t) {
        int col = t*16 + l15;
        float bv = b_n2[col];
        #pragma unroll
        for (int i = 0; i < 4; ++i) {
            int n = n0 + quad*4 + i;
            h_out[(size_t)n*HID + col] = h[(size_t)n*HID + col] + acc[t][i] + bv;
        }
    }
}

extern "C" void kernel_launch(void* const* d_in, const int* in_sizes, int n_in,
                              void* d_out, int out_size, void* d_ws, size_t ws_size,
                              hipStream_t stream) {
    const float* h          = (const float*)d_in[0];
    const float* x          = (const float*)d_in[1];
    const float* edge_attr  = (const float*)d_in[2];
    const int*   edge_index = (const int*)  d_in[3];
    const int*   mask       = (const int*)  d_in[4];
    const float* W_e1 = (const float*)d_in[5];
    const float* b_e1 = (const float*)d_in[6];
    const float* W_e2 = (const float*)d_in[7];
    const float* b_e2 = (const float*)d_in[8];
    const float* W_g  = (const float*)d_in[9];
    const float* b_g  = (const float*)d_in[10];
    const float* W_n1 = (const float*)d_in[11];
    const float* b_n1 = (const float*)d_in[12];
    const float* W_n2 = (const float*)d_in[13];
    const float* b_n2 = (const float*)d_in[14];
    const float* W_x1 = (const float*)d_in[15];
    const float* b_x1 = (const float*)d_in[16];
    const float* W_x2 = (const float*)d_in[17];

    char* ws = (char*)d_ws;
    float* agg = (float*)ws;                       ws += (size_t)NN*HID*4;
    float* dxv = (float*)ws;                       ws += (size_t)NN*3*4;
    int*   counts = (int*)ws;                      ws += (size_t)NN*4;
    int*   cursor = (int*)ws;                      ws += (size_t)NN*4;
    int2*  pair2  = (int2*)ws;                     ws += (size_t)NE*8;
    float4* geom4 = (float4*)ws;                   ws += (size_t)NE*16;
    unsigned short* attrb = (unsigned short*)ws;   ws += (size_t)NE*4*2;
    unsigned short* PD    = (unsigned short*)ws;   ws += (size_t)NN*HID*2;
    unsigned short* PS    = (unsigned short*)ws;   ws += (size_t)NN*HID*2;
    unsigned short* WT1d  = (unsigned short*)ws;   ws += (size_t)HID*HID*2;
    unsigned short* WT1s  = (unsigned short*)ws;   ws += (size_t)HID*HID*2;
    unsigned short* WT1r  = (unsigned short*)ws;   ws += (size_t)HID*32*2;
    unsigned short* WT_e2 = (unsigned short*)ws;   ws += (size_t)HID*HID*2;
    unsigned short* WT_x1 = (unsigned short*)ws;   ws += (size_t)HID*HID*2;
    unsigned short* WT_n1 = (unsigned short*)ws;   ws += (size_t)HID*KN1*2;
    unsigned short* WT_n2 = (unsigned short*)ws;   ws += (size_t)HID*HID*2;

    hipMemsetAsync(agg, 0, ((size_t)NN*HID + (size_t)NN*3)*sizeof(float), stream);
    hipMemsetAsync(counts, 0, (size_t)NN*sizeof(int), stream);

    prep_hist_kernel<<<128 + NE/320, 320, 0, stream>>>(
        W_e1, W_e2, W_x1, W_n1, W_n2,
        WT1d, WT1s, WT1r, WT_e2, WT_x1, WT_n1, WT_n2,
        edge_index, counts);

    scan_kernel<<<1, 1024, 0, stream>>>(counts, cursor);

    build_pd_kernel<<<PD_BLOCKS + NE/256, 256, 0, stream>>>(
        edge_index, x, edge_attr, cursor, pair2, geom4, attrb,
        h, b_e1, WT1d, WT1s, PD, PS);

    egnn_edge_mfma<<<NE/64, 128, 0, stream>>>(
        pair2, geom4, attrb, PD, PS, WT1r, WT_e2, WT_x1,
        b_e2, W_g, b_g, b_x1, W_x2, agg, dxv);

    float* h_out = (float*)d_out;
    float* x_out = h_out + (size_t)NN*HID;

    egnn_node_mfma<<<NN/16, 64, 0, stream>>>(
        h, x, mask, agg, dxv, WT_n1, b_n1, WT_n2, b_n2, h_out, x_out);
}

// Round 14
// 492.445 us; speedup vs baseline: 1.0644x; 1.0369x over previous
//
#include <hip/hip_runtime.h>
#include <hip/hip_bf16.h>
#include <math.h>

#define HID 128
#define NUM_G 20
#define EF 4
#define NN 20000
#define NE 640000
#define KN1 256           // node GEMM1 K
#define TS 136            // LDS stride (bf16): 272B rows -> near-conflict-free

typedef __attribute__((ext_vector_type(8))) short short8;
typedef __attribute__((ext_vector_type(4))) short short4v;
typedef __attribute__((ext_vector_type(4))) float floatx4;
typedef __attribute__((ext_vector_type(4))) unsigned int uintx4;

__device__ __forceinline__ float silu_f(float v){
    return v * __builtin_amdgcn_rcpf(1.0f + __expf(-v));
}
__device__ __forceinline__ float sigm_f(float v){
    return __builtin_amdgcn_rcpf(1.0f + __expf(-v));
}
__device__ __forceinline__ float tanh_f(float v){
    return 1.0f - 2.0f * __builtin_amdgcn_rcpf(1.0f + __expf(2.0f * v));
}
__device__ __forceinline__ unsigned short f2bf(float v){
    unsigned int u = __float_as_uint(v);
    u = (u + 0x7fffu + ((u >> 16) & 1u)) >> 16;
    return (unsigned short)u;
}
__device__ __forceinline__ float bf2f(unsigned short u){
    return __uint_as_float(((unsigned int)u) << 16);
}
__device__ __forceinline__ unsigned int pk2(float a, float b){
    __hip_bfloat162 h = __float22bfloat162_rn(make_float2(a, b));
    return *(unsigned int*)&h;
}
__device__ __forceinline__ float2 up2(unsigned int u){
    __hip_bfloat162 h = *(__hip_bfloat162*)&u;
    return __bfloat1622float2(h);
}

// ---- fused: weight transpose/bf16 (blocks 0..127) ∥ dst histogram (blocks 128+) ----
__global__ __launch_bounds__(320) void prep_hist_kernel(
    const float* __restrict__ W_e1, const float* __restrict__ W_e2,
    const float* __restrict__ W_x1, const float* __restrict__ W_n1,
    const float* __restrict__ W_n2,
    unsigned short* __restrict__ WT1d, unsigned short* __restrict__ WT1s,
    unsigned short* __restrict__ WT1r,
    unsigned short* __restrict__ WT_e2, unsigned short* __restrict__ WT_x1,
    unsigned short* __restrict__ WT_n1, unsigned short* __restrict__ WT_n2,
    const int* __restrict__ edge_index, int* __restrict__ counts)
{
    int t = threadIdx.x;
    if (blockIdx.x < 128) {
        int n = blockIdx.x;
        if (t < HID) {
            WT1d[n*HID + t] = f2bf(W_e1[t*HID + n]);
            WT1s[n*HID + t] = f2bf(W_e1[(HID+t)*HID + n]);
            WT_e2[n*HID + t] = f2bf(W_e2[t*HID + n]);
            WT_x1[n*HID + t] = f2bf(W_x1[t*HID + n]);
            WT_n2[n*HID + t] = f2bf(W_n2[t*HID + n]);
        }
        if (t < 32) WT1r[n*32 + t] = (t < NUM_G+EF) ? f2bf(W_e1[(256+t)*HID + n]) : (unsigned short)0;
        if (t < KN1) WT_n1[n*KN1 + t] = f2bf(W_n1[t*HID + n]);
    } else {
        int e = (blockIdx.x - 128) * 320 + t;   // NE = 2000*320
        atomicAdd(&counts[edge_index[NE + e]], 1);
    }
}

__global__ __launch_bounds__(1024) void scan_kernel(
    const int* __restrict__ counts, int* __restrict__ cursor)
{
    __shared__ int part[1024];
    const int t = threadIdx.x;
    const int CH = (NN + 1023) / 1024;   // 20
    int base = t * CH;
    int s = 0;
    for (int i = 0; i < CH; ++i) { int idx = base + i; if (idx < NN) s += counts[idx]; }
    part[t] = s; __syncthreads();
    for (int off = 1; off < 1024; off <<= 1) {
        int v = (t >= off) ? part[t - off] : 0;
        __syncthreads();
        part[t] += v;
        __syncthreads();
    }
    int run = (t == 0) ? 0 : part[t - 1];
    for (int i = 0; i < CH; ++i) {
        int idx = base + i;
        if (idx < NN) { cursor[idx] = run; run += counts[idx]; }
    }
}

// ---- Kernel C: pd (blocks 0..312, 4 waves x 16 nodes) ∥ build (blocks 313+) ----
#define PD_BLOCKS ((NN + 63) / 64)    // 313
__global__ __launch_bounds__(256) void build_pd_kernel(
    const int* __restrict__ edge_index, const float* __restrict__ x,
    const float* __restrict__ edge_attr, int* __restrict__ cursor,
    int2* __restrict__ pair2, float4* __restrict__ geom4,
    unsigned short* __restrict__ attrb,
    const float* __restrict__ h, const float* __restrict__ b_e1,
    const unsigned short* __restrict__ WT1d, const unsigned short* __restrict__ WT1s,
    unsigned short* __restrict__ PD, unsigned short* __restrict__ PS)
{
    __shared__ __align__(16) unsigned short T[4][16*TS];

    if (blockIdx.x >= PD_BLOCKS) {
        // ---- build part ----
        int e = (blockIdx.x - PD_BLOCKS) * 256 + threadIdx.x;
        int s = edge_index[e];
        int d = edge_index[NE + e];
        int pos = atomicAdd(&cursor[d], 1);
        float rx = x[d*3+0] - x[s*3+0];
        float ry = x[d*3+1] - x[s*3+1];
        float rz = x[d*3+2] - x[s*3+2];
        float r  = sqrtf(rx*rx + ry*ry + rz*rz + 1e-8f);
        pair2[pos] = make_int2(s, d);
        geom4[pos] = make_float4(rx, ry, rz, r);
        short4v a;
        #pragma unroll
        for (int j = 0; j < 4; ++j) a[j] = (short)f2bf(edge_attr[(size_t)e*EF + j]);
        *(short4v*)(attrb + (size_t)pos*4) = a;
        return;
    }

    // ---- pd part: 4 autonomous waves, 16 nodes each ----
    const int wv   = threadIdx.x >> 6;
    const int lane = threadIdx.x & 63;
    const int quad = lane >> 4;
    const int l15  = lane & 15;
    int node = blockIdx.x * 64 + wv * 16 + l15;
    if (node >= NN) node = NN - 1;     // duplicate-write guard (same data)
    unsigned short* Tw = &T[wv][0];

    short8 ah[4];
    #pragma unroll
    for (int kc = 0; kc < 4; ++kc) {
        const float* p = h + (size_t)node*HID + kc*32 + quad*8;
        float4 f0 = *(const float4*)(p);
        float4 f1 = *(const float4*)(p + 4);
        uintx4 u;
        u[0] = pk2(f0.x, f0.y); u[1] = pk2(f0.z, f0.w);
        u[2] = pk2(f1.x, f1.y); u[3] = pk2(f1.z, f1.w);
        ah[kc] = __builtin_bit_cast(short8, u);
    }

    floatx4 ad[8], as[8];
    #pragma unroll
    for (int t = 0; t < 8; ++t) { ad[t] = (floatx4){0,0,0,0}; as[t] = (floatx4){0,0,0,0}; }
    #pragma unroll
    for (int kc = 0; kc < 4; ++kc) {
        #pragma unroll
        for (int t = 0; t < 8; ++t) {
            short8 bd = *(const short8*)(WT1d + (size_t)(t*16+l15)*HID + kc*32 + quad*8);
            short8 bs = *(const short8*)(WT1s + (size_t)(t*16+l15)*HID + kc*32 + quad*8);
            ad[t] = __builtin_amdgcn_mfma_f32_16x16x32_bf16(ah[kc], bd, ad[t], 0, 0, 0);
            as[t] = __builtin_amdgcn_mfma_f32_16x16x32_bf16(ah[kc], bs, as[t], 0, 0, 0);
        }
    }
    #pragma unroll
    for (int t = 0; t < 8; ++t) {
        int col = t*16 + l15;
        float bv = b_e1[col];
        #pragma unroll
        for (int i = 0; i < 4; ++i)
            Tw[(quad*4+i)*TS + col] = f2bf(ad[t][i] + bv);
    }
    __builtin_amdgcn_wave_barrier();
    #pragma unroll
    for (int kc = 0; kc < 4; ++kc)
        *(short8*)(PD + (size_t)node*HID + kc*32 + quad*8) =
            *(const short8*)(&Tw[l15*TS + kc*32 + quad*8]);
    __builtin_amdgcn_wave_barrier();
    #pragma unroll
    for (int t = 0; t < 8; ++t) {
        int col = t*16 + l15;
        #pragma unroll
        for (int i = 0; i < 4; ++i)
            Tw[(quad*4+i)*TS + col] = f2bf(as[t][i]);
    }
    __builtin_amdgcn_wave_barrier();
    #pragma unroll
    for (int kc = 0; kc < 4; ++kc)
        *(short8*)(PS + (size_t)node*HID + kc*32 + quad*8) =
            *(const short8*)(&Tw[l15*TS + kc*32 + quad*8]);
}

// ---- edge kernel: 128 threads = 2 autonomous waves, 32 sorted edges/wave.
// launch_bounds (128,3): arg=4 clamps VGPR to 64 -> spill cliff (R6/R10); arg=3 ok.
// Msg atomics issued right after GEMM3 MFMA (B-loads already in flight) so the
// ~500-cyc epilogue + vec-reduce cover the atomic drain before endpgm.
__global__ __launch_bounds__(128, 3) void egnn_edge_mfma(
    const int2* __restrict__ pair2, const float4* __restrict__ geom4,
    const unsigned short* __restrict__ attrb,
    const unsigned short* __restrict__ PD, const unsigned short* __restrict__ PS,
    const unsigned short* __restrict__ WT1r,
    const unsigned short* __restrict__ WT_e2,
    const unsigned short* __restrict__ WT_x1,
    const float* __restrict__ b_e2,
    const float* __restrict__ W_g,  const float* __restrict__ b_g,
    const float* __restrict__ b_x1, const float* __restrict__ W_x2,
    float* __restrict__ agg, float* __restrict__ dxv)
{
    __shared__ __align__(16) unsigned short T[2][32*TS];   // rbf-acc, then m2
    __shared__ int   s_dst[2][33];
    __shared__ float s_g[2][32];
    __shared__ float s_vec[2][96];

    const int wv   = threadIdx.x >> 6;
    const int lane = threadIdx.x & 63;
    const int quad = lane >> 4;
    const int l15  = lane & 15;
    const int e0   = (blockIdx.x * 2 + wv) * 32;

    unsigned short* Tw = &T[wv][0];

    // --- coalesced meta (lanes 0..31 own one edge each) ---
    int   sreg = 0, dreg = 0;
    float rxr = 0.f, ryr = 0.f, rzr = 0.f, rreg = 0.f;
    if (lane < 32) {
        int2  p = pair2[e0 + lane];
        float4 g = geom4[e0 + lane];
        sreg = p.x; dreg = p.y;
        rxr = g.x; ryr = g.y; rzr = g.z; rreg = g.w;
        s_dst[wv][lane] = dreg;
    }
    if (lane == 32) s_dst[wv][32] = -1;

    const int   nd0 = __shfl(dreg, l15);
    const int   ns0 = __shfl(sreg, l15);
    const float rr0 = __shfl(rreg, l15);
    const int   nd1 = __shfl(dreg, 16 + l15);
    const int   ns1 = __shfl(sreg, 16 + l15);
    const float rr1 = __shfl(rreg, 16 + l15);

    // --- issue long-latency PD/PS gathers first ---
    short8 pdv0[4], psv0[4], pdv1[4], psv1[4];
    #pragma unroll
    for (int kc = 0; kc < 4; ++kc) {
        pdv0[kc] = *(const short8*)(PD + (size_t)nd0*HID + kc*32 + quad*8);
        psv0[kc] = *(const short8*)(PS + (size_t)ns0*HID + kc*32 + quad*8);
        pdv1[kc] = *(const short8*)(PD + (size_t)nd1*HID + kc*32 + quad*8);
        psv1[kc] = *(const short8*)(PS + (size_t)ns1*HID + kc*32 + quad*8);
    }

    // rbf fragments (packed-pair converts); attr from sorted bf16 stream
    short8 ar0, ar1;
    {
        const float step  = 10.0f / 19.0f;
        const float coeff = -0.5f / (step*step);
        uintx4 u0, u1;
        #pragma unroll
        for (int jp = 0; jp < 4; ++jp) {
            float v[4];
            #pragma unroll
            for (int half = 0; half < 2; ++half) {
                float rr = half ? rr1 : rr0;
                int rowbase = e0 + (half ? 16 : 0) + l15;
                #pragma unroll
                for (int q = 0; q < 2; ++q) {
                    int col = quad*8 + jp*2 + q;
                    float val = 0.f;
                    if (col < NUM_G) {
                        float d = rr - step*(float)col;
                        val = __expf(coeff*d*d);
                    } else if (col < NUM_G+EF) {
                        val = bf2f(attrb[(size_t)rowbase*4 + (col-NUM_G)]);
                    }
                    v[half*2 + q] = val;
                }
            }
            u0[jp] = pk2(v[0], v[1]);
            u1[jp] = pk2(v[2], v[3]);
        }
        ar0 = __builtin_bit_cast(short8, u0);
        ar1 = __builtin_bit_cast(short8, u1);
    }

    floatx4 acc0[8], acc1[8];
    #pragma unroll
    for (int t = 0; t < 8; ++t) { acc0[t] = (floatx4){0,0,0,0}; acc1[t] = (floatx4){0,0,0,0}; }
    #pragma unroll
    for (int t = 0; t < 8; ++t) {
        short8 b = *(const short8*)(WT1r + (size_t)(t*16+l15)*32 + quad*8);
        acc0[t] = __builtin_amdgcn_mfma_f32_16x16x32_bf16(ar0, b, acc0[t], 0, 0, 0);
        acc1[t] = __builtin_amdgcn_mfma_f32_16x16x32_bf16(ar1, b, acc1[t], 0, 0, 0);
    }
    #pragma unroll
    for (int t = 0; t < 8; ++t) {
        int col = t*16 + l15;
        #pragma unroll
        for (int i = 0; i < 4; i += 2) {
            unsigned int u0 = pk2(acc0[t][i], acc0[t][i+1]);
            unsigned int u1 = pk2(acc1[t][i], acc1[t][i+1]);
            Tw[(quad*4+i)*TS + col]        = (unsigned short)u0;
            Tw[(quad*4+i+1)*TS + col]      = (unsigned short)(u0 >> 16);
            Tw[(16+quad*4+i)*TS + col]     = (unsigned short)u1;
            Tw[(16+quad*4+i+1)*TS + col]   = (unsigned short)(u1 >> 16);
        }
    }
    __builtin_amdgcn_wave_barrier();

    // layer-1 finalize: m1 = silu(PD[dst]+PS[src]+rbf)  (bias folded in PD)
    short8 a2[8];
    #pragma unroll
    for (int kc = 0; kc < 4; ++kc) {
        uintx4 rv0 = __builtin_bit_cast(uintx4, *(const short8*)(&Tw[l15*TS + kc*32 + quad*8]));
        uintx4 rv1 = __builtin_bit_cast(uintx4, *(const short8*)(&Tw[(16+l15)*TS + kc*32 + quad*8]));
        uintx4 pu0 = __builtin_bit_cast(uintx4, pdv0[kc]);
        uintx4 su0 = __builtin_bit_cast(uintx4, psv0[kc]);
        uintx4 pu1 = __builtin_bit_cast(uintx4, pdv1[kc]);
        uintx4 su1 = __builtin_bit_cast(uintx4, psv1[kc]);
        uintx4 o0, o1;
        #pragma unroll
        for (int w = 0; w < 4; ++w) {
            float2 p0 = up2(pu0[w]), s0 = up2(su0[w]), r0 = up2(rv0[w]);
            float2 p1 = up2(pu1[w]), s1 = up2(su1[w]), r1 = up2(rv1[w]);
            o0[w] = pk2(silu_f(p0.x + s0.x + r0.x), silu_f(p0.y + s0.y + r0.y));
            o1[w] = pk2(silu_f(p1.x + s1.x + r1.x), silu_f(p1.y + s1.y + r1.y));
        }
        a2[kc]   = __builtin_bit_cast(short8, o0);
        a2[4+kc] = __builtin_bit_cast(short8, o1);
    }
    __builtin_amdgcn_wave_barrier();

    // --- GEMM2: m2 = silu(m1 @ W_e2 + b), gate; B loaded once for both tiles ---
    #pragma unroll
    for (int t = 0; t < 8; ++t) { acc0[t] = (floatx4){0,0,0,0}; acc1[t] = (floatx4){0,0,0,0}; }
    #pragma unroll
    for (int kc = 0; kc < 4; ++kc) {
        #pragma unroll
        for (int t = 0; t < 8; ++t) {
            short8 b = *(const short8*)(WT_e2 + (size_t)(t*16+l15)*HID + kc*32 + quad*8);
            acc0[t] = __builtin_amdgcn_mfma_f32_16x16x32_bf16(a2[kc],   b, acc0[t], 0, 0, 0);
            acc1[t] = __builtin_amdgcn_mfma_f32_16x16x32_bf16(a2[4+kc], b, acc1[t], 0, 0, 0);
        }
    }
    {
        float gp0[4] = {0,0,0,0}, gp1[4] = {0,0,0,0};
        #pragma unroll
        for (int t = 0; t < 8; ++t) {
            int col = t*16 + l15;
            float bv = b_e2[col];
            float wgv = W_g[col];
            #pragma unroll
            for (int i = 0; i < 4; i += 2) {
                float m20a = silu_f(acc0[t][i]   + bv);
                float m20b = silu_f(acc0[t][i+1] + bv);
                float m21a = silu_f(acc1[t][i]   + bv);
                float m21b = silu_f(acc1[t][i+1] + bv);
                gp0[i] += m20a * wgv; gp0[i+1] += m20b * wgv;
                gp1[i] += m21a * wgv; gp1[i+1] += m21b * wgv;
                unsigned int u0 = pk2(m20a, m20b);
                unsigned int u1 = pk2(m21a, m21b);
                Tw[(quad*4+i)*TS + col]      = (unsigned short)u0;
                Tw[(quad*4+i+1)*TS + col]    = (unsigned short)(u0 >> 16);
                Tw[(16+quad*4+i)*TS + col]   = (unsigned short)u1;
                Tw[(16+quad*4+i+1)*TS + col] = (unsigned short)(u1 >> 16);
            }
        }
        const float bg0 = b_g[0];
        #pragma unroll
        for (int i = 0; i < 4; ++i) {
            gp0[i] += __shfl_xor(gp0[i], 1); gp0[i] += __shfl_xor(gp0[i], 2);
            gp0[i] += __shfl_xor(gp0[i], 4); gp0[i] += __shfl_xor(gp0[i], 8);
            gp1[i] += __shfl_xor(gp1[i], 1); gp1[i] += __shfl_xor(gp1[i], 2);
            gp1[i] += __shfl_xor(gp1[i], 4); gp1[i] += __shfl_xor(gp1[i], 8);
        }
        if (l15 == 0) {
            #pragma unroll
            for (int i = 0; i < 4; ++i) {
                s_g[wv][quad*4 + i]      = sigm_f(gp0[i] + bg0);
                s_g[wv][16 + quad*4 + i] = sigm_f(gp1[i] + bg0);
            }
        }
    }
    __builtin_amdgcn_wave_barrier();

    // --- GEMM3: coord head (m2 from T, both tiles) ---
    #pragma unroll
    for (int kc = 0; kc < 4; ++kc) {
        a2[kc]   = *(const short8*)(&Tw[l15*TS + kc*32 + quad*8]);
        a2[4+kc] = *(const short8*)(&Tw[(16+l15)*TS + kc*32 + quad*8]);
    }
    #pragma unroll
    for (int t = 0; t < 8; ++t) { acc0[t] = (floatx4){0,0,0,0}; acc1[t] = (floatx4){0,0,0,0}; }
    #pragma unroll
    for (int kc = 0; kc < 4; ++kc) {
        #pragma unroll
        for (int t = 0; t < 8; ++t) {
            short8 b = *(const short8*)(WT_x1 + (size_t)(t*16+l15)*HID + kc*32 + quad*8);
            acc0[t] = __builtin_amdgcn_mfma_f32_16x16x32_bf16(a2[kc],   b, acc0[t], 0, 0, 0);
            acc1[t] = __builtin_amdgcn_mfma_f32_16x16x32_bf16(a2[4+kc], b, acc1[t], 0, 0, 0);
        }
    }

    // --- msg segmented reduce + atomics NOW (drain overlaps GEMM3 epilogue) ---
    {
        float am0 = 0.f, am1 = 0.f;
        #pragma unroll
        for (int r = 0; r < 32; ++r) {
            unsigned int pv = *(const unsigned int*)(&Tw[r*TS + lane*2]);
            float gr = s_g[wv][r];
            float2 f = up2(pv);
            am0 += f.x * gr;
            am1 += f.y * gr;
            int dr = s_dst[wv][r];
            if (dr != s_dst[wv][r+1]) {
                atomicAdd(&agg[(size_t)dr*HID + lane*2],     am0);
                atomicAdd(&agg[(size_t)dr*HID + lane*2 + 1], am1);
                am0 = 0.f; am1 = 0.f;
            }
        }
    }

    {
        float cp0[4] = {0,0,0,0}, cp1[4] = {0,0,0,0};
        #pragma unroll
        for (int t = 0; t < 8; ++t) {
            int col = t*16 + l15;
            float bv = b_x1[col];
            float wx = W_x2[col];
            #pragma unroll
            for (int i = 0; i < 4; ++i) {
                cp0[i] += silu_f(acc0[t][i] + bv) * wx;
                cp1[i] += silu_f(acc1[t][i] + bv) * wx;
            }
        }
        #pragma unroll
        for (int i = 0; i < 4; ++i) {
            cp0[i] += __shfl_xor(cp0[i], 1); cp0[i] += __shfl_xor(cp0[i], 2);
            cp0[i] += __shfl_xor(cp0[i], 4); cp0[i] += __shfl_xor(cp0[i], 8);
            cp1[i] += __shfl_xor(cp1[i], 1); cp1[i] += __shfl_xor(cp1[i], 2);
            cp1[i] += __shfl_xor(cp1[i], 4); cp1[i] += __shfl_xor(cp1[i], 8);
        }
        if (l15 < 3) {
            #pragma unroll
            for (int i = 0; i < 4; ++i) {
                int r0 = quad*4 + i;
                int r1 = 16 + quad*4 + i;
                float relc0 = (l15 == 0) ? __shfl(rxr, r0) : ((l15 == 1) ? __shfl(ryr, r0) : __shfl(rzr, r0));
                float relc1 = (l15 == 0) ? __shfl(rxr, r1) : ((l15 == 1) ? __shfl(ryr, r1) : __shfl(rzr, r1));
                float rv0 = __shfl(rreg, r0);
                float rv1 = __shfl(rreg, r1);
                s_vec[wv][r0*3 + l15] = relc0 * __builtin_amdgcn_rcpf(rv0 + 1.0f) * tanh_f(cp0[i]);
                s_vec[wv][r1*3 + l15] = relc1 * __builtin_amdgcn_rcpf(rv1 + 1.0f) * tanh_f(cp1[i]);
            }
        }
    }
    __builtin_amdgcn_wave_barrier();

    if (lane < 3) {
        float a = 0.f;
        #pragma unroll
        for (int r = 0; r < 32; ++r) {
            a += s_vec[wv][r*3 + lane];
            int dr = s_dst[wv][r];
            if (dr != s_dst[wv][r+1]) {
                atomicAdd(&dxv[(size_t)dr*3 + lane], a);
                a = 0.f;
            }
        }
    }
}

// ---- node kernel: ONE WAVE per block, 16 nodes ----
__global__ __launch_bounds__(64, 4) void egnn_node_mfma(
    const float* __restrict__ h, const float* __restrict__ x,
    const int* __restrict__ mask,
    const float* __restrict__ agg, const float* __restrict__ dxv,
    const unsigned short* __restrict__ WT_n1, const float* __restrict__ b_n1,
    const unsigned short* __restrict__ WT_n2, const float* __restrict__ b_n2,
    float* __restrict__ h_out, float* __restrict__ x_out)
{
    __shared__ __align__(16) unsigned short T[16*TS];

    const int lane = threadIdx.x;
    const int quad = lane >> 4;
    const int l15  = lane & 15;
    const int n0   = blockIdx.x * 16;

    if (lane < 48) {
        int r = lane / 3, c = lane % 3;
        int n = n0 + r;
        x_out[n*3 + c] = x[n*3 + c] + dxv[n*3 + c] * (float)mask[n];
    }

    const int node = n0 + l15;
    short8 a1[8];
    #pragma unroll
    for (int kc = 0; kc < 4; ++kc) {
        const float* p = agg + (size_t)node*HID + kc*32 + quad*8;
        float4 f0 = *(const float4*)(p);
        float4 f1 = *(const float4*)(p + 4);
        uintx4 u;
        u[0] = pk2(f0.x, f0.y); u[1] = pk2(f0.z, f0.w);
        u[2] = pk2(f1.x, f1.y); u[3] = pk2(f1.z, f1.w);
        a1[kc] = __builtin_bit_cast(short8, u);
    }
    #pragma unroll
    for (int kc = 0; kc < 4; ++kc) {
        const float* p = h + (size_t)node*HID + kc*32 + quad*8;
        float4 f0 = *(const float4*)(p);
        float4 f1 = *(const float4*)(p + 4);
        uintx4 u;
        u[0] = pk2(f0.x, f0.y); u[1] = pk2(f0.z, f0.w);
        u[2] = pk2(f1.x, f1.y); u[3] = pk2(f1.z, f1.w);
        a1[4+kc] = __builtin_bit_cast(short8, u);
    }

    floatx4 acc[8];
    #pragma unroll
    for (int t = 0; t < 8; ++t) acc[t] = (floatx4){0,0,0,0};
    #pragma unroll
    for (int kc = 0; kc < 8; ++kc) {
        #pragma unroll
        for (int t = 0; t < 8; ++t) {
            short8 b = *(const short8*)(WT_n1 + (size_t)(t*16+l15)*KN1 + kc*32 + quad*8);
            acc[t] = __builtin_amdgcn_mfma_f32_16x16x32_bf16(a1[kc], b, acc[t], 0, 0, 0);
        }
    }
    #pragma unroll
    for (int t = 0; t < 8; ++t) {
        int col = t*16 + l15;
        float bv = b_n1[col];
        #pragma unroll
        for (int i = 0; i < 4; i += 2) {
            unsigned int u = pk2(silu_f(acc[t][i] + bv), silu_f(acc[t][i+1] + bv));
            T[(quad*4+i)*TS + col]   = (unsigned short)u;
            T[(quad*4+i+1)*TS + col] = (unsigned short)(u >> 16);
        }
    }
    __builtin_amdgcn_wave_barrier();

    short8 a2[4];
    #pragma unroll
    for (int kc = 0; kc < 4; ++kc)
        a2[kc] = *(const short8*)(&T[l15*TS + kc*32 + quad*8]);
    #pragma unroll
    for (int t = 0; t < 8; ++t) acc[t] = (floatx4){0,0,0,0};
    #pragma unroll
    for (int kc = 0; kc < 4; ++kc) {
        #pragma unroll
        for (int t = 0; t < 8; ++t) {
            short8 b = *(const short8*)(WT_n2 + (size_t)(t*16+l15)*HID + kc*32 + quad*8);
            acc[t] = __builtin_amdgcn_mfma_f32_16x16x32_bf16(a2[kc], b, acc[t], 0, 0, 0);
        }
    }
    #pragma unroll
    for (int t = 0; t < 8; ++t) {
        int col = t*16 + l15;
        float bv = b_n2[col];
        #pragma unroll
        for (int i = 0; i < 4; ++i) {
            int n = n0 + quad*4 + i;
            h_out[(size_t)n*HID + col] = h[(size_t)n*HID + col] + acc[t][i] + bv;
        }
    }
}

extern "C" void kernel_launch(void* const* d_in, const int* in_sizes, int n_in,
                              void* d_out, int out_size, void* d_ws, size_t ws_size,
                              hipStream_t stream) {
    const float* h          = (const float*)d_in[0];
    const float* x          = (const float*)d_in[1];
    const float* edge_attr  = (const float*)d_in[2];
    const int*   edge_index = (const int*)  d_in[3];
    const int*   mask       = (const int*)  d_in[4];
    const float* W_e1 = (const float*)d_in[5];
    const float* b_e1 = (const float*)d_in[6];
    const float* W_e2 = (const float*)d_in[7];
    const float* b_e2 = (const float*)d_in[8];
    const float* W_g  = (const float*)d_in[9];
    const float* b_g  = (const float*)d_in[10];
    const float* W_n1 = (const float*)d_in[11];
    const float* b_n1 = (const float*)d_in[12];
    const float* W_n2 = (const float*)d_in[13];
    const float* b_n2 = (const float*)d_in[14];
    const float* W_x1 = (const float*)d_in[15];
    const float* b_x1 = (const float*)d_in[16];
    const float* W_x2 = (const float*)d_in[17];

    char* ws = (char*)d_ws;
    float* agg = (float*)ws;                       ws += (size_t)NN*HID*4;
    float* dxv = (float*)ws;                       ws += (size_t)NN*3*4;
    int*   counts = (int*)ws;                      ws += (size_t)NN*4;
    int*   cursor = (int*)ws;                      ws += (size_t)NN*4;
    int2*  pair2  = (int2*)ws;                     ws += (size_t)NE*8;
    float4* geom4 = (float4*)ws;                   ws += (size_t)NE*16;
    unsigned short* attrb = (unsigned short*)ws;   ws += (size_t)NE*4*2;
    unsigned short* PD    = (unsigned short*)ws;   ws += (size_t)NN*HID*2;
    unsigned short* PS    = (unsigned short*)ws;   ws += (size_t)NN*HID*2;
    unsigned short* WT1d  = (unsigned short*)ws;   ws += (size_t)HID*HID*2;
    unsigned short* WT1s  = (unsigned short*)ws;   ws += (size_t)HID*HID*2;
    unsigned short* WT1r  = (unsigned short*)ws;   ws += (size_t)HID*32*2;
    unsigned short* WT_e2 = (unsigned short*)ws;   ws += (size_t)HID*HID*2;
    unsigned short* WT_x1 = (unsigned short*)ws;   ws += (size_t)HID*HID*2;
    unsigned short* WT_n1 = (unsigned short*)ws;   ws += (size_t)HID*KN1*2;
    unsigned short* WT_n2 = (unsigned short*)ws;   ws += (size_t)HID*HID*2;

    hipMemsetAsync(agg, 0, ((size_t)NN*HID + (size_t)NN*3)*sizeof(float), stream);
    hipMemsetAsync(counts, 0, (size_t)NN*sizeof(int), stream);

    prep_hist_kernel<<<128 + NE/320, 320, 0, stream>>>(
        W_e1, W_e2, W_x1, W_n1, W_n2,
        WT1d, WT1s, WT1r, WT_e2, WT_x1, WT_n1, WT_n2,
        edge_index, counts);

    scan_kernel<<<1, 1024, 0, stream>>>(counts, cursor);

    build_pd_kernel<<<PD_BLOCKS + NE/256, 256, 0, stream>>>(
        edge_index, x, edge_attr, cursor, pair2, geom4, attrb,
        h, b_e1, WT1d, WT1s, PD, PS);

    egnn_edge_mfma<<<NE/64, 128, 0, stream>>>(
        pair2, geom4, attrb, PD, PS, WT1r, WT_e2, WT_x1,
        b_e2, W_g, b_g, b_x1, W_x2, agg, dxv);

    float* h_out = (float*)d_out;
    float* x_out = h_out + (size_t)NN*HID;

    egnn_node_mfma<<<NN/16, 64, 0, stream>>>(
        h, x, mask, agg, dxv, WT_n1, b_n1, WT_n2, b_n2, h_out, x_out);
}

// Round 15
// 491.012 us; speedup vs baseline: 1.0675x; 1.0029x over previous
//
#include <hip/hip_runtime.h>
#include <hip/hip_bf16.h>
#include <math.h>

#define HID 128
#define NUM_G 20
#define EF 4
#define NN 20000
#define NE 640000
#define KN1 256           // node GEMM1 K
#define TS 136            // LDS stride (bf16): 272B rows -> near-conflict-free

typedef __attribute__((ext_vector_type(8))) short short8;
typedef __attribute__((ext_vector_type(4))) short short4v;
typedef __attribute__((ext_vector_type(4))) float floatx4;
typedef __attribute__((ext_vector_type(4))) unsigned int uintx4;

__device__ __forceinline__ float silu_f(float v){
    return v * __builtin_amdgcn_rcpf(1.0f + __expf(-v));
}
__device__ __forceinline__ float sigm_f(float v){
    return __builtin_amdgcn_rcpf(1.0f + __expf(-v));
}
__device__ __forceinline__ float tanh_f(float v){
    return 1.0f - 2.0f * __builtin_amdgcn_rcpf(1.0f + __expf(2.0f * v));
}
__device__ __forceinline__ unsigned short f2bf(float v){
    unsigned int u = __float_as_uint(v);
    u = (u + 0x7fffu + ((u >> 16) & 1u)) >> 16;
    return (unsigned short)u;
}
__device__ __forceinline__ float bf2f(unsigned short u){
    return __uint_as_float(((unsigned int)u) << 16);
}
__device__ __forceinline__ unsigned int pk2(float a, float b){
    __hip_bfloat162 h = __float22bfloat162_rn(make_float2(a, b));
    return *(unsigned int*)&h;
}
__device__ __forceinline__ float2 up2(unsigned int u){
    __hip_bfloat162 h = *(__hip_bfloat162*)&u;
    return __bfloat1622float2(h);
}

// ---- fused: weight transpose/bf16 (blocks 0..127) ∥ dst histogram (blocks 128+) ----
__global__ __launch_bounds__(320) void prep_hist_kernel(
    const float* __restrict__ W_e1, const float* __restrict__ W_e2,
    const float* __restrict__ W_x1, const float* __restrict__ W_n1,
    const float* __restrict__ W_n2,
    unsigned short* __restrict__ WT1d, unsigned short* __restrict__ WT1s,
    unsigned short* __restrict__ WT1r,
    unsigned short* __restrict__ WT_e2, unsigned short* __restrict__ WT_x1,
    unsigned short* __restrict__ WT_n1, unsigned short* __restrict__ WT_n2,
    const int* __restrict__ edge_index, int* __restrict__ counts)
{
    int t = threadIdx.x;
    if (blockIdx.x < 128) {
        int n = blockIdx.x;
        if (t < HID) {
            WT1d[n*HID + t] = f2bf(W_e1[t*HID + n]);
            WT1s[n*HID + t] = f2bf(W_e1[(HID+t)*HID + n]);
            WT_e2[n*HID + t] = f2bf(W_e2[t*HID + n]);
            WT_x1[n*HID + t] = f2bf(W_x1[t*HID + n]);
            WT_n2[n*HID + t] = f2bf(W_n2[t*HID + n]);
        }
        if (t < 32) WT1r[n*32 + t] = (t < NUM_G+EF) ? f2bf(W_e1[(256+t)*HID + n]) : (unsigned short)0;
        if (t < KN1) WT_n1[n*KN1 + t] = f2bf(W_n1[t*HID + n]);
    } else {
        int e = (blockIdx.x - 128) * 320 + t;   // NE = 2000*320
        atomicAdd(&counts[edge_index[NE + e]], 1);
    }
}

__global__ __launch_bounds__(1024) void scan_kernel(
    const int* __restrict__ counts, int* __restrict__ cursor)
{
    __shared__ int part[1024];
    const int t = threadIdx.x;
    const int CH = (NN + 1023) / 1024;   // 20
    int base = t * CH;
    int s = 0;
    for (int i = 0; i < CH; ++i) { int idx = base + i; if (idx < NN) s += counts[idx]; }
    part[t] = s; __syncthreads();
    for (int off = 1; off < 1024; off <<= 1) {
        int v = (t >= off) ? part[t - off] : 0;
        __syncthreads();
        part[t] += v;
        __syncthreads();
    }
    int run = (t == 0) ? 0 : part[t - 1];
    for (int i = 0; i < CH; ++i) {
        int idx = base + i;
        if (idx < NN) { cursor[idx] = run; run += counts[idx]; }
    }
}

// ---- Kernel C: pd (blocks 0..312, 4 waves x 16 nodes) ∥ build (blocks 313+) ----
#define PD_BLOCKS ((NN + 63) / 64)    // 313
__global__ __launch_bounds__(256) void build_pd_kernel(
    const int* __restrict__ edge_index, const float* __restrict__ x,
    const float* __restrict__ edge_attr, int* __restrict__ cursor,
    int2* __restrict__ pair2, float4* __restrict__ geom4,
    unsigned short* __restrict__ attrb,
    const float* __restrict__ h, const float* __restrict__ b_e1,
    const unsigned short* __restrict__ WT1d, const unsigned short* __restrict__ WT1s,
    unsigned short* __restrict__ PD, unsigned short* __restrict__ PS)
{
    __shared__ __align__(16) unsigned short T[4][16*TS];

    if (blockIdx.x >= PD_BLOCKS) {
        // ---- build part ----
        int e = (blockIdx.x - PD_BLOCKS) * 256 + threadIdx.x;
        int s = edge_index[e];
        int d = edge_index[NE + e];
        int pos = atomicAdd(&cursor[d], 1);
        float rx = x[d*3+0] - x[s*3+0];
        float ry = x[d*3+1] - x[s*3+1];
        float rz = x[d*3+2] - x[s*3+2];
        float r  = sqrtf(rx*rx + ry*ry + rz*rz + 1e-8f);
        pair2[pos] = make_int2(s, d);
        geom4[pos] = make_float4(rx, ry, rz, r);
        short4v a;
        #pragma unroll
        for (int j = 0; j < 4; ++j) a[j] = (short)f2bf(edge_attr[(size_t)e*EF + j]);
        *(short4v*)(attrb + (size_t)pos*4) = a;
        return;
    }

    // ---- pd part: 4 autonomous waves, 16 nodes each ----
    const int wv   = threadIdx.x >> 6;
    const int lane = threadIdx.x & 63;
    const int quad = lane >> 4;
    const int l15  = lane & 15;
    int node = blockIdx.x * 64 + wv * 16 + l15;
    if (node >= NN) node = NN - 1;     // duplicate-write guard (same data)
    unsigned short* Tw = &T[wv][0];

    short8 ah[4];
    #pragma unroll
    for (int kc = 0; kc < 4; ++kc) {
        const float* p = h + (size_t)node*HID + kc*32 + quad*8;
        float4 f0 = *(const float4*)(p);
        float4 f1 = *(const float4*)(p + 4);
        uintx4 u;
        u[0] = pk2(f0.x, f0.y); u[1] = pk2(f0.z, f0.w);
        u[2] = pk2(f1.x, f1.y); u[3] = pk2(f1.z, f1.w);
        ah[kc] = __builtin_bit_cast(short8, u);
    }

    floatx4 ad[8], as[8];
    #pragma unroll
    for (int t = 0; t < 8; ++t) { ad[t] = (floatx4){0,0,0,0}; as[t] = (floatx4){0,0,0,0}; }
    #pragma unroll
    for (int kc = 0; kc < 4; ++kc) {
        #pragma unroll
        for (int t = 0; t < 8; ++t) {
            short8 bd = *(const short8*)(WT1d + (size_t)(t*16+l15)*HID + kc*32 + quad*8);
            short8 bs = *(const short8*)(WT1s + (size_t)(t*16+l15)*HID + kc*32 + quad*8);
            ad[t] = __builtin_amdgcn_mfma_f32_16x16x32_bf16(ah[kc], bd, ad[t], 0, 0, 0);
            as[t] = __builtin_amdgcn_mfma_f32_16x16x32_bf16(ah[kc], bs, as[t], 0, 0, 0);
        }
    }
    #pragma unroll
    for (int t = 0; t < 8; ++t) {
        int col = t*16 + l15;
        float bv = b_e1[col];
        #pragma unroll
        for (int i = 0; i < 4; ++i)
            Tw[(quad*4+i)*TS + col] = f2bf(ad[t][i] + bv);
    }
    __builtin_amdgcn_wave_barrier();
    #pragma unroll
    for (int kc = 0; kc < 4; ++kc)
        *(short8*)(PD + (size_t)node*HID + kc*32 + quad*8) =
            *(const short8*)(&Tw[l15*TS + kc*32 + quad*8]);
    __builtin_amdgcn_wave_barrier();
    #pragma unroll
    for (int t = 0; t < 8; ++t) {
        int col = t*16 + l15;
        #pragma unroll
        for (int i = 0; i < 4; ++i)
            Tw[(quad*4+i)*TS + col] = f2bf(as[t][i]);
    }
    __builtin_amdgcn_wave_barrier();
    #pragma unroll
    for (int kc = 0; kc < 4; ++kc)
        *(short8*)(PS + (size_t)node*HID + kc*32 + quad*8) =
            *(const short8*)(&Tw[l15*TS + kc*32 + quad*8]);
}

// ---- edge kernel: 128 threads = 2 autonomous waves, 32 sorted edges/wave.
// launch_bounds (128,3): arg=4 clamps VGPR to 64 -> spill cliff (R6/R10); arg=3 ok.
// XCD swizzle: grid 10000 = 8*1250; give each XCD one contiguous sorted-edge
// range so PD/PS rows + agg atomic lines stay in one XCD's L2.
__global__ __launch_bounds__(128, 3) void egnn_edge_mfma(
    const int2* __restrict__ pair2, const float4* __restrict__ geom4,
    const unsigned short* __restrict__ attrb,
    const unsigned short* __restrict__ PD, const unsigned short* __restrict__ PS,
    const unsigned short* __restrict__ WT1r,
    const unsigned short* __restrict__ WT_e2,
    const unsigned short* __restrict__ WT_x1,
    const float* __restrict__ b_e2,
    const float* __restrict__ W_g,  const float* __restrict__ b_g,
    const float* __restrict__ b_x1, const float* __restrict__ W_x2,
    float* __restrict__ agg, float* __restrict__ dxv)
{
    __shared__ __align__(16) unsigned short T[2][32*TS];   // rbf-acc, then m2
    __shared__ int   s_dst[2][33];
    __shared__ float s_g[2][32];
    __shared__ float s_vec[2][96];

    const int wv   = threadIdx.x >> 6;
    const int lane = threadIdx.x & 63;
    const int quad = lane >> 4;
    const int l15  = lane & 15;
    // XCD-contiguous remap: consecutive blocks on one XCD process consecutive edges
    const int bid  = (int)(blockIdx.x & 7) * 1250 + (int)(blockIdx.x >> 3);
    const int e0   = (bid * 2 + wv) * 32;

    unsigned short* Tw = &T[wv][0];

    // --- coalesced meta (lanes 0..31 own one edge each) ---
    int   sreg = 0, dreg = 0;
    float rxr = 0.f, ryr = 0.f, rzr = 0.f, rreg = 0.f;
    if (lane < 32) {
        int2  p = pair2[e0 + lane];
        float4 g = geom4[e0 + lane];
        sreg = p.x; dreg = p.y;
        rxr = g.x; ryr = g.y; rzr = g.z; rreg = g.w;
        s_dst[wv][lane] = dreg;
    }
    if (lane == 32) s_dst[wv][32] = -1;

    const int   nd0 = __shfl(dreg, l15);
    const int   ns0 = __shfl(sreg, l15);
    const float rr0 = __shfl(rreg, l15);
    const int   nd1 = __shfl(dreg, 16 + l15);
    const int   ns1 = __shfl(sreg, 16 + l15);
    const float rr1 = __shfl(rreg, 16 + l15);

    // --- issue long-latency PD/PS gathers first ---
    short8 pdv0[4], psv0[4], pdv1[4], psv1[4];
    #pragma unroll
    for (int kc = 0; kc < 4; ++kc) {
        pdv0[kc] = *(const short8*)(PD + (size_t)nd0*HID + kc*32 + quad*8);
        psv0[kc] = *(const short8*)(PS + (size_t)ns0*HID + kc*32 + quad*8);
        pdv1[kc] = *(const short8*)(PD + (size_t)nd1*HID + kc*32 + quad*8);
        psv1[kc] = *(const short8*)(PS + (size_t)ns1*HID + kc*32 + quad*8);
    }

    // rbf fragments (packed-pair converts); attr from sorted bf16 stream
    short8 ar0, ar1;
    {
        const float step  = 10.0f / 19.0f;
        const float coeff = -0.5f / (step*step);
        uintx4 u0, u1;
        #pragma unroll
        for (int jp = 0; jp < 4; ++jp) {
            float v[4];
            #pragma unroll
            for (int half = 0; half < 2; ++half) {
                float rr = half ? rr1 : rr0;
                int rowbase = e0 + (half ? 16 : 0) + l15;
                #pragma unroll
                for (int q = 0; q < 2; ++q) {
                    int col = quad*8 + jp*2 + q;
                    float val = 0.f;
                    if (col < NUM_G) {
                        float d = rr - step*(float)col;
                        val = __expf(coeff*d*d);
                    } else if (col < NUM_G+EF) {
                        val = bf2f(attrb[(size_t)rowbase*4 + (col-NUM_G)]);
                    }
                    v[half*2 + q] = val;
                }
            }
            u0[jp] = pk2(v[0], v[1]);
            u1[jp] = pk2(v[2], v[3]);
        }
        ar0 = __builtin_bit_cast(short8, u0);
        ar1 = __builtin_bit_cast(short8, u1);
    }

    floatx4 acc0[8], acc1[8];
    #pragma unroll
    for (int t = 0; t < 8; ++t) { acc0[t] = (floatx4){0,0,0,0}; acc1[t] = (floatx4){0,0,0,0}; }
    #pragma unroll
    for (int t = 0; t < 8; ++t) {
        short8 b = *(const short8*)(WT1r + (size_t)(t*16+l15)*32 + quad*8);
        acc0[t] = __builtin_amdgcn_mfma_f32_16x16x32_bf16(ar0, b, acc0[t], 0, 0, 0);
        acc1[t] = __builtin_amdgcn_mfma_f32_16x16x32_bf16(ar1, b, acc1[t], 0, 0, 0);
    }
    #pragma unroll
    for (int t = 0; t < 8; ++t) {
        int col = t*16 + l15;
        #pragma unroll
        for (int i = 0; i < 4; i += 2) {
            unsigned int u0 = pk2(acc0[t][i], acc0[t][i+1]);
            unsigned int u1 = pk2(acc1[t][i], acc1[t][i+1]);
            Tw[(quad*4+i)*TS + col]        = (unsigned short)u0;
            Tw[(quad*4+i+1)*TS + col]      = (unsigned short)(u0 >> 16);
            Tw[(16+quad*4+i)*TS + col]     = (unsigned short)u1;
            Tw[(16+quad*4+i+1)*TS + col]   = (unsigned short)(u1 >> 16);
        }
    }
    __builtin_amdgcn_wave_barrier();

    // layer-1 finalize: m1 = silu(PD[dst]+PS[src]+rbf)  (bias folded in PD)
    short8 a2[8];
    #pragma unroll
    for (int kc = 0; kc < 4; ++kc) {
        uintx4 rv0 = __builtin_bit_cast(uintx4, *(const short8*)(&Tw[l15*TS + kc*32 + quad*8]));
        uintx4 rv1 = __builtin_bit_cast(uintx4, *(const short8*)(&Tw[(16+l15)*TS + kc*32 + quad*8]));
        uintx4 pu0 = __builtin_bit_cast(uintx4, pdv0[kc]);
        uintx4 su0 = __builtin_bit_cast(uintx4, psv0[kc]);
        uintx4 pu1 = __builtin_bit_cast(uintx4, pdv1[kc]);
        uintx4 su1 = __builtin_bit_cast(uintx4, psv1[kc]);
        uintx4 o0, o1;
        #pragma unroll
        for (int w = 0; w < 4; ++w) {
            float2 p0 = up2(pu0[w]), s0 = up2(su0[w]), r0 = up2(rv0[w]);
            float2 p1 = up2(pu1[w]), s1 = up2(su1[w]), r1 = up2(rv1[w]);
            o0[w] = pk2(silu_f(p0.x + s0.x + r0.x), silu_f(p0.y + s0.y + r0.y));
            o1[w] = pk2(silu_f(p1.x + s1.x + r1.x), silu_f(p1.y + s1.y + r1.y));
        }
        a2[kc]   = __builtin_bit_cast(short8, o0);
        a2[4+kc] = __builtin_bit_cast(short8, o1);
    }
    __builtin_amdgcn_wave_barrier();

    // --- GEMM2: m2 = silu(m1 @ W_e2 + b), gate; B loaded once for both tiles ---
    #pragma unroll
    for (int t = 0; t < 8; ++t) { acc0[t] = (floatx4){0,0,0,0}; acc1[t] = (floatx4){0,0,0,0}; }
    #pragma unroll
    for (int kc = 0; kc < 4; ++kc) {
        #pragma unroll
        for (int t = 0; t < 8; ++t) {
            short8 b = *(const short8*)(WT_e2 + (size_t)(t*16+l15)*HID + kc*32 + quad*8);
            acc0[t] = __builtin_amdgcn_mfma_f32_16x16x32_bf16(a2[kc],   b, acc0[t], 0, 0, 0);
            acc1[t] = __builtin_amdgcn_mfma_f32_16x16x32_bf16(a2[4+kc], b, acc1[t], 0, 0, 0);
        }
    }
    {
        float gp0[4] = {0,0,0,0}, gp1[4] = {0,0,0,0};
        #pragma unroll
        for (int t = 0; t < 8; ++t) {
            int col = t*16 + l15;
            float bv = b_e2[col];
            float wgv = W_g[col];
            #pragma unroll
            for (int i = 0; i < 4; i += 2) {
                float m20a = silu_f(acc0[t][i]   + bv);
                float m20b = silu_f(acc0[t][i+1] + bv);
                float m21a = silu_f(acc1[t][i]   + bv);
                float m21b = silu_f(acc1[t][i+1] + bv);
                gp0[i] += m20a * wgv; gp0[i+1] += m20b * wgv;
                gp1[i] += m21a * wgv; gp1[i+1] += m21b * wgv;
                unsigned int u0 = pk2(m20a, m20b);
                unsigned int u1 = pk2(m21a, m21b);
                Tw[(quad*4+i)*TS + col]      = (unsigned short)u0;
                Tw[(quad*4+i+1)*TS + col]    = (unsigned short)(u0 >> 16);
                Tw[(16+quad*4+i)*TS + col]   = (unsigned short)u1;
                Tw[(16+quad*4+i+1)*TS + col] = (unsigned short)(u1 >> 16);
            }
        }
        const float bg0 = b_g[0];
        #pragma unroll
        for (int i = 0; i < 4; ++i) {
            gp0[i] += __shfl_xor(gp0[i], 1); gp0[i] += __shfl_xor(gp0[i], 2);
            gp0[i] += __shfl_xor(gp0[i], 4); gp0[i] += __shfl_xor(gp0[i], 8);
            gp1[i] += __shfl_xor(gp1[i], 1); gp1[i] += __shfl_xor(gp1[i], 2);
            gp1[i] += __shfl_xor(gp1[i], 4); gp1[i] += __shfl_xor(gp1[i], 8);
        }
        if (l15 == 0) {
            #pragma unroll
            for (int i = 0; i < 4; ++i) {
                s_g[wv][quad*4 + i]      = sigm_f(gp0[i] + bg0);
                s_g[wv][16 + quad*4 + i] = sigm_f(gp1[i] + bg0);
            }
        }
    }
    __builtin_amdgcn_wave_barrier();

    // --- GEMM3: coord head (m2 from T, both tiles) ---
    #pragma unroll
    for (int kc = 0; kc < 4; ++kc) {
        a2[kc]   = *(const short8*)(&Tw[l15*TS + kc*32 + quad*8]);
        a2[4+kc] = *(const short8*)(&Tw[(16+l15)*TS + kc*32 + quad*8]);
    }
    #pragma unroll
    for (int t = 0; t < 8; ++t) { acc0[t] = (floatx4){0,0,0,0}; acc1[t] = (floatx4){0,0,0,0}; }
    #pragma unroll
    for (int kc = 0; kc < 4; ++kc) {
        #pragma unroll
        for (int t = 0; t < 8; ++t) {
            short8 b = *(const short8*)(WT_x1 + (size_t)(t*16+l15)*HID + kc*32 + quad*8);
            acc0[t] = __builtin_amdgcn_mfma_f32_16x16x32_bf16(a2[kc],   b, acc0[t], 0, 0, 0);
            acc1[t] = __builtin_amdgcn_mfma_f32_16x16x32_bf16(a2[4+kc], b, acc1[t], 0, 0, 0);
        }
    }

    // --- msg segmented reduce + atomics NOW (drain overlaps GEMM3 epilogue) ---
    {
        float am0 = 0.f, am1 = 0.f;
        #pragma unroll
        for (int r = 0; r < 32; ++r) {
            unsigned int pv = *(const unsigned int*)(&Tw[r*TS + lane*2]);
            float gr = s_g[wv][r];
            float2 f = up2(pv);
            am0 += f.x * gr;
            am1 += f.y * gr;
            int dr = s_dst[wv][r];
            if (dr != s_dst[wv][r+1]) {
                atomicAdd(&agg[(size_t)dr*HID + lane*2],     am0);
                atomicAdd(&agg[(size_t)dr*HID + lane*2 + 1], am1);
                am0 = 0.f; am1 = 0.f;
            }
        }
    }

    {
        float cp0[4] = {0,0,0,0}, cp1[4] = {0,0,0,0};
        #pragma unroll
        for (int t = 0; t < 8; ++t) {
            int col = t*16 + l15;
            float bv = b_x1[col];
            float wx = W_x2[col];
            #pragma unroll
            for (int i = 0; i < 4; ++i) {
                cp0[i] += silu_f(acc0[t][i] + bv) * wx;
                cp1[i] += silu_f(acc1[t][i] + bv) * wx;
            }
        }
        #pragma unroll
        for (int i = 0; i < 4; ++i) {
            cp0[i] += __shfl_xor(cp0[i], 1); cp0[i] += __shfl_xor(cp0[i], 2);
            cp0[i] += __shfl_xor(cp0[i], 4); cp0[i] += __shfl_xor(cp0[i], 8);
            cp1[i] += __shfl_xor(cp1[i], 1); cp1[i] += __shfl_xor(cp1[i], 2);
            cp1[i] += __shfl_xor(cp1[i], 4); cp1[i] += __shfl_xor(cp1[i], 8);
        }
        if (l15 < 3) {
            #pragma unroll
            for (int i = 0; i < 4; ++i) {
                int r0 = quad*4 + i;
                int r1 = 16 + quad*4 + i;
                float relc0 = (l15 == 0) ? __shfl(rxr, r0) : ((l15 == 1) ? __shfl(ryr, r0) : __shfl(rzr, r0));
                float relc1 = (l15 == 0) ? __shfl(rxr, r1) : ((l15 == 1) ? __shfl(ryr, r1) : __shfl(rzr, r1));
                float rv0 = __shfl(rreg, r0);
                float rv1 = __shfl(rreg, r1);
                s_vec[wv][r0*3 + l15] = relc0 * __builtin_amdgcn_rcpf(rv0 + 1.0f) * tanh_f(cp0[i]);
                s_vec[wv][r1*3 + l15] = relc1 * __builtin_amdgcn_rcpf(rv1 + 1.0f) * tanh_f(cp1[i]);
            }
        }
    }
    __builtin_amdgcn_wave_barrier();

    if (lane < 3) {
        float a = 0.f;
        #pragma unroll
        for (int r = 0; r < 32; ++r) {
            a += s_vec[wv][r*3 + lane];
            int dr = s_dst[wv][r];
            if (dr != s_dst[wv][r+1]) {
                atomicAdd(&dxv[(size_t)dr*3 + lane], a);
                a = 0.f;
            }
        }
    }
}

// ---- node kernel: ONE WAVE per block, 16 nodes ----
__global__ __launch_bounds__(64, 4) void egnn_node_mfma(
    const float* __restrict__ h, const float* __restrict__ x,
    const int* __restrict__ mask,
    const float* __restrict__ agg, const float* __restrict__ dxv,
    const unsigned short* __restrict__ WT_n1, const float* __restrict__ b_n1,
    const unsigned short* __restrict__ WT_n2, const float* __restrict__ b_n2,
    float* __restrict__ h_out, float* __restrict__ x_out)
{
    __shared__ __align__(16) unsigned short T[16*TS];

    const int lane = threadIdx.x;
    const int quad = lane >> 4;
    const int l15  = lane & 15;
    const int n0   = blockIdx.x * 16;

    if (lane < 48) {
        int r = lane / 3, c = lane % 3;
        int n = n0 + r;
        x_out[n*3 + c] = x[n*3 + c] + dxv[n*3 + c] * (float)mask[n];
    }

    const int node = n0 + l15;
    short8 a1[8];
    #pragma unroll
    for (int kc = 0; kc < 4; ++kc) {
        const float* p = agg + (size_t)node*HID + kc*32 + quad*8;
        float4 f0 = *(const float4*)(p);
        float4 f1 = *(const float4*)(p + 4);
        uintx4 u;
        u[0] = pk2(f0.x, f0.y); u[1] = pk2(f0.z, f0.w);
        u[2] = pk2(f1.x, f1.y); u[3] = pk2(f1.z, f1.w);
        a1[kc] = __builtin_bit_cast(short8, u);
    }
    #pragma unroll
    for (int kc = 0; kc < 4; ++kc) {
        const float* p = h + (size_t)node*HID + kc*32 + quad*8;
        float4 f0 = *(const float4*)(p);
        float4 f1 = *(const float4*)(p + 4);
        uintx4 u;
        u[0] = pk2(f0.x, f0.y); u[1] = pk2(f0.z, f0.w);
        u[2] = pk2(f1.x, f1.y); u[3] = pk2(f1.z, f1.w);
        a1[4+kc] = __builtin_bit_cast(short8, u);
    }

    floatx4 acc[8];
    #pragma unroll
    for (int t = 0; t < 8; ++t) acc[t] = (floatx4){0,0,0,0};
    #pragma unroll
    for (int kc = 0; kc < 8; ++kc) {
        #pragma unroll
        for (int t = 0; t < 8; ++t) {
            short8 b = *(const short8*)(WT_n1 + (size_t)(t*16+l15)*KN1 + kc*32 + quad*8);
            acc[t] = __builtin_amdgcn_mfma_f32_16x16x32_bf16(a1[kc], b, acc[t], 0, 0, 0);
        }
    }
    #pragma unroll
    for (int t = 0; t < 8; ++t) {
        int col = t*16 + l15;
        float bv = b_n1[col];
        #pragma unroll
        for (int i = 0; i < 4; i += 2) {
            unsigned int u = pk2(silu_f(acc[t][i] + bv), silu_f(acc[t][i+1] + bv));
            T[(quad*4+i)*TS + col]   = (unsigned short)u;
            T[(quad*4+i+1)*TS + col] = (unsigned short)(u >> 16);
        }
    }
    __builtin_amdgcn_wave_barrier();

    short8 a2[4];
    #pragma unroll
    for (int kc = 0; kc < 4; ++kc)
        a2[kc] = *(const short8*)(&T[l15*TS + kc*32 + quad*8]);
    #pragma unroll
    for (int t = 0; t < 8; ++t) acc[t] = (floatx4){0,0,0,0};
    #pragma unroll
    for (int kc = 0; kc < 4; ++kc) {
        #pragma unroll
        for (int t = 0; t < 8; ++t) {
            short8 b = *(const short8*)(WT_n2 + (size_t)(t*16+l15)*HID + kc*32 + quad*8);
            acc[t] = __builtin_amdgcn_mfma_f32_16x16x32_bf16(a2[kc], b, acc[t], 0, 0, 0);
        }
    }
    #pragma unroll
    for (int t = 0; t < 8; ++t) {
        int col = t*16 + l15;
        float bv = b_n2[col];
        #pragma unroll
        for (int i = 0; i < 4; ++i) {
            int n = n0 + quad*4 + i;
            h_out[(size_t)n*HID + col] = h[(size_t)n*HID + col] + acc[t][i] + bv;
        }
    }
}

extern "C" void kernel_launch(void* const* d_in, const int* in_sizes, int n_in,
                              void* d_out, int out_size, void* d_ws, size_t ws_size,
                              hipStream_t stream) {
    const float* h          = (const float*)d_in[0];
    const float* x          = (const float*)d_in[1];
    const float* edge_attr  = (const float*)d_in[2];
    const int*   edge_index = (const int*)  d_in[3];
    const int*   mask       = (const int*)  d_in[4];
    const float* W_e1 = (const float*)d_in[5];
    const float* b_e1 = (const float*)d_in[6];
    const float* W_e2 = (const float*)d_in[7];
    const float* b_e2 = (const float*)d_in[8];
    const float* W_g  = (const float*)d_in[9];
    const float* b_g  = (const float*)d_in[10];
    const float* W_n1 = (const float*)d_in[11];
    const float* b_n1 = (const float*)d_in[12];
    const float* W_n2 = (const float*)d_in[13];
    const float* b_n2 = (const float*)d_in[14];
    const float* W_x1 = (const float*)d_in[15];
    const float* b_x1 = (const float*)d_in[16];
    const float* W_x2 = (const float*)d_in[17];

    char* ws = (char*)d_ws;
    float* agg = (float*)ws;                       ws += (size_t)NN*HID*4;
    float* dxv = (float*)ws;                       ws += (size_t)NN*3*4;
    int*   counts = (int*)ws;                      ws += (size_t)NN*4;
    int*   cursor = (int*)ws;                      ws += (size_t)NN*4;
    int2*  pair2  = (int2*)ws;                     ws += (size_t)NE*8;
    float4* geom4 = (float4*)ws;                   ws += (size_t)NE*16;
    unsigned short* attrb = (unsigned short*)ws;   ws += (size_t)NE*4*2;
    unsigned short* PD    = (unsigned short*)ws;   ws += (size_t)NN*HID*2;
    unsigned short* PS    = (unsigned short*)ws;   ws += (size_t)NN*HID*2;
    unsigned short* WT1d  = (unsigned short*)ws;   ws += (size_t)HID*HID*2;
    unsigned short* WT1s  = (unsigned short*)ws;   ws += (size_t)HID*HID*2;
    unsigned short* WT1r  = (unsigned short*)ws;   ws += (size_t)HID*32*2;
    unsigned short* WT_e2 = (unsigned short*)ws;   ws += (size_t)HID*HID*2;
    unsigned short* WT_x1 = (unsigned short*)ws;   ws += (size_t)HID*HID*2;
    unsigned short* WT_n1 = (unsigned short*)ws;   ws += (size_t)HID*KN1*2;
    unsigned short* WT_n2 = (unsigned short*)ws;   ws += (size_t)HID*HID*2;

    hipMemsetAsync(agg, 0, ((size_t)NN*HID + (size_t)NN*3)*sizeof(float), stream);
    hipMemsetAsync(counts, 0, (size_t)NN*sizeof(int), stream);

    prep_hist_kernel<<<128 + NE/320, 320, 0, stream>>>(
        W_e1, W_e2, W_x1, W_n1, W_n2,
        WT1d, WT1s, WT1r, WT_e2, WT_x1, WT_n1, WT_n2,
        edge_index, counts);

    scan_kernel<<<1, 1024, 0, stream>>>(counts, cursor);

    build_pd_kernel<<<PD_BLOCKS + NE/256, 256, 0, stream>>>(
        edge_index, x, edge_attr, cursor, pair2, geom4, attrb,
        h, b_e1, WT1d, WT1s, PD, PS);

    egnn_edge_mfma<<<NE/64, 128, 0, stream>>>(
        pair2, geom4, attrb, PD, PS, WT1r, WT_e2, WT_x1,
        b_e2, W_g, b_g, b_x1, W_x2, agg, dxv);

    float* h_out = (float*)d_out;
    float* x_out = h_out + (size_t)NN*HID;

    egnn_node_mfma<<<NN/16, 64, 0, stream>>>(
        h, x, mask, agg, dxv, WT_n1, b_n1, WT_n2, b_n2, h_out, x_out);
}